// Round 14
// baseline (673.320 us; speedup 1.0000x reference)
//
#include <hip/hip_runtime.h>
#include <math.h>

// ---------------------------------------------------------------------------
// StandardMoELayer on MI355X.
// Precision: fp16x3 split-MFMA upstream of router; bf16 MFMA post-router.
// R14: router fused into LN1 (bit-exact summation-order reproduction of the
// old router_kernel: thread (w,l) holds router's (lane=l, j=w) term; j-sum
// in ascending order then identical shuffle-xor tree) — kills a launch and a
// 32MB re-read. attn: s_setprio(1) around MFMA clusters (guide: +4-7%).
// ---------------------------------------------------------------------------

typedef __attribute__((ext_vector_type(4))) float f32x4;
typedef __attribute__((ext_vector_type(8))) _Float16 f16x8;
typedef __attribute__((ext_vector_type(4))) _Float16 f16x4;
typedef __attribute__((ext_vector_type(8))) short bf16x8;

#define DEVI static __device__ __forceinline__

DEVI unsigned short f2bf(float f) {
  unsigned int u = __builtin_bit_cast(unsigned int, f);
  return (unsigned short)((u + 0x7fffu + ((u >> 16) & 1u)) >> 16);
}

DEVI f32x4 fzero4() { f32x4 z; z[0]=0.f; z[1]=0.f; z[2]=0.f; z[3]=0.f; return z; }

DEVI void splitf16(float v, _Float16* hi, _Float16* lo) {
  _Float16 h = (_Float16)v;
  *hi = h;
  *lo = (_Float16)(v - (float)h);
}

DEVI void gload16(const void* g, void* l) {
  __builtin_amdgcn_global_load_lds(
      (__attribute__((address_space(1))) void*)(g),
      (__attribute__((address_space(3))) void*)(l), 16, 0, 0);
}

// ---------------------------------------------------------------------------
// fused elementwise prep: x/ipw/ow fp16-split + w1/w2 bf16 cast, one launch
// ---------------------------------------------------------------------------
DEVI void do_split(const float* __restrict__ in, _Float16* __restrict__ oh,
                   _Float16* __restrict__ ol, float scale, int i) {
  float4 v = ((const float4*)in)[i];
  f16x4 hv, lv; _Float16 hh, ll;
  splitf16(v.x * scale, &hh, &ll); hv[0]=hh; lv[0]=ll;
  splitf16(v.y * scale, &hh, &ll); hv[1]=hh; lv[1]=ll;
  splitf16(v.z * scale, &hh, &ll); hv[2]=hh; lv[2]=ll;
  splitf16(v.w * scale, &hh, &ll); hv[3]=hh; lv[3]=ll;
  ((f16x4*)oh)[i] = hv;
  ((f16x4*)ol)[i] = lv;
}

DEVI void do_castbf(const float* __restrict__ in, unsigned short* __restrict__ o,
                    int i) {
  float4 v = ((const float4*)in)[i];
  ushort4 r;
  r.x = f2bf(v.x); r.y = f2bf(v.y); r.z = f2bf(v.z); r.w = f2bf(v.w);
  ((ushort4*)o)[i] = r;
}

__global__ void prep_kernel(const float* __restrict__ x,
                            _Float16* __restrict__ Xh, _Float16* __restrict__ Xl,
                            const float* __restrict__ ipw,
                            _Float16* __restrict__ Wih, _Float16* __restrict__ Wil,
                            const float* __restrict__ ow,
                            _Float16* __restrict__ Woh, _Float16* __restrict__ Wol,
                            const float* __restrict__ w1, unsigned short* __restrict__ w1b,
                            const float* __restrict__ w2, unsigned short* __restrict__ w2b) {
  int b = blockIdx.x, tid = threadIdx.x;
  if (b < 8192)        do_split(x,   Xh,  Xl,  2048.0f, b * 256 + tid);
  else if (b < 11264)  do_split(ipw, Wih, Wil, 1024.0f, (b - 8192) * 256 + tid);
  else if (b < 12288)  do_split(ow,  Woh, Wol, 1024.0f, (b - 11264) * 256 + tid);
  else if (b < 20480)  do_castbf(w1, w1b, (b - 12288) * 256 + tid);
  else                 do_castbf(w2, w2b, (b - 20480) * 256 + tid);
}

// ---------------------------------------------------------------------------
// fp16x3 GEMM: C[M=8192,N] = A[M,K] * W[N,K]^T  (A scaled 2^11, W scaled 2^10)
// 128x128 tile, BK=32, 512 threads = 8 waves (2x4), 64x32 out per wave.
// Double-buffered global_load_lds pipeline (vmcnt(0)+syncthreads, replay-safe)
// XCD-chunked grid. EPI 0: two-pass LDS-restage coalesced Q/K/V^T split-store.
// EPI 1: +bias +res -> fp32 out.
// ---------------------------------------------------------------------------
template<int EPI>
__global__ __launch_bounds__(512) void gemm_f16x3(
    const _Float16* __restrict__ Ah, const _Float16* __restrict__ Al,
    const _Float16* __restrict__ Bh, const _Float16* __restrict__ Bl,
    const float* __restrict__ bias, int N, int K,
    float* __restrict__ out_f, const float* __restrict__ res,
    _Float16* __restrict__ Qh, _Float16* __restrict__ Ql,
    _Float16* __restrict__ Kh, _Float16* __restrict__ Kl,
    _Float16* __restrict__ Vh, _Float16* __restrict__ Vl) {
  __shared__ __align__(16) char smem[65536];  // 2 buf x (4 arrays x 128 x 64 B)
  const int tid = threadIdx.x;
  const int lane = tid & 63, wave = tid >> 6;   // 0..7
  const int wm = wave >> 2, wn = wave & 3;      // 2 x 4 wave grid
  const int qr = lane & 15, lq = lane >> 4;

  // XCD-chunked block remap (nwg % 8 == 0 here)
  const int xcd = blockIdx.x & 7, idx = blockIdx.x >> 3;
  const int colsPerX = (N >> 7) >> 3;
  const int rowb = idx / colsPerX;
  const int colb = xcd * colsPerX + (idx - rowb * colsPerX);
  const int rowBase = rowb * 128, colBase = colb * 128;

  // staging: 1 granule-swizzled 16B chunk per array per thread.
  const char* gsrc[4];
  unsigned ldso[4];
  {
    const int row = tid >> 2;
    const int gs = (tid & 3) ^ ((row >> 1) & 3);
#pragma unroll
    for (int a = 0; a < 4; ++a) {
      const _Float16* basep = (a == 0) ? Ah : (a == 1) ? Al : (a == 2) ? Bh : Bl;
      int R0 = (a < 2) ? rowBase : colBase;
      gsrc[a] = (const char*)(basep + (size_t)(R0 + row) * K) + gs * 16;
      ldso[a] = a * 8192 + wave * 1024;  // wave-uniform
    }
  }

  f32x4 acc[4][2];
#pragma unroll
  for (int m = 0; m < 4; ++m)
#pragma unroll
    for (int n = 0; n < 2; ++n) acc[m][n] = fzero4();

  const int gfr = (qr >> 1) & 3;  // frag granule swizzle term
  const int NT = K >> 5;
  // prologue: stage tile 0 into buf 0
#pragma unroll
  for (int a = 0; a < 4; ++a) gload16(gsrc[a], smem + ldso[a]);
#pragma unroll
  for (int a = 0; a < 4; ++a) gsrc[a] += 64;

  for (int kt = 0; kt < NT; ++kt) {
    asm volatile("s_waitcnt vmcnt(0)" ::: "memory");  // explicit DMA drain
    __syncthreads();  // tile kt resident in buf[kt&1]
    const unsigned cur = (unsigned)(kt & 1) << 15;
    const unsigned nxt = cur ^ 32768u;
    if (kt + 1 < NT) {
#pragma unroll
      for (int a = 0; a < 4; ++a) gload16(gsrc[a], smem + nxt + ldso[a]);
#pragma unroll
      for (int a = 0; a < 4; ++a) gsrc[a] += 64;
    }
    f16x8 ahf[4], alf[4], bhf[2], blf[2];
#pragma unroll
    for (int mt = 0; mt < 4; ++mt) {
      unsigned off = cur + (wm * 64 + mt * 16 + qr) * 64 + ((lq ^ gfr) * 16);
      ahf[mt] = *(const f16x8*)(smem + off);
      alf[mt] = *(const f16x8*)(smem + 8192 + off);
    }
#pragma unroll
    for (int nt = 0; nt < 2; ++nt) {
      unsigned off = cur + (wn * 32 + nt * 16 + qr) * 64 + ((lq ^ gfr) * 16);
      bhf[nt] = *(const f16x8*)(smem + 16384 + off);
      blf[nt] = *(const f16x8*)(smem + 24576 + off);
    }
#pragma unroll
    for (int mt = 0; mt < 4; ++mt)
#pragma unroll
      for (int nt = 0; nt < 2; ++nt) {
        f32x4 c = acc[mt][nt];
        c = __builtin_amdgcn_mfma_f32_16x16x32_f16(ahf[mt], bhf[nt], c, 0, 0, 0);
        c = __builtin_amdgcn_mfma_f32_16x16x32_f16(ahf[mt], blf[nt], c, 0, 0, 0);
        c = __builtin_amdgcn_mfma_f32_16x16x32_f16(alf[mt], bhf[nt], c, 0, 0, 0);
        acc[mt][nt] = c;
      }
  }

  const float inv21 = 1.0f / 2097152.0f;  // 2^-21
  float biasv[2];
#pragma unroll
  for (int nt = 0; nt < 2; ++nt) biasv[nt] = bias[colBase + wn * 32 + nt * 16 + qr];

  if (EPI == 0) {
    __syncthreads();  // staging LDS reusable now
    const int sect = colBase >> 10;                // 0=Q 1=K 2=V (block-uniform)
    const int hhBase = (colBase & 1023) >> 6;
    const int t0 = rowBase >> 3;
    _Float16* L = (_Float16*)smem;                 // 16384 fp16 = 32 KB
    _Float16* dstH = (sect == 0) ? Qh : (sect == 1) ? Kh : Vh;
    _Float16* dstL = (sect == 0) ? Ql : (sect == 1) ? Kl : Vl;
#pragma unroll
    for (int pass = 0; pass < 2; ++pass) {
      if (pass) __syncthreads();
      // scatter acc into LDS in output-linear layout
#pragma unroll
      for (int mt = 0; mt < 4; ++mt)
#pragma unroll
        for (int nt = 0; nt < 2; ++nt)
#pragma unroll
          for (int r = 0; r < 4; ++r) {
            int rl = wm * 64 + mt * 16 + lq * 4 + r;
            int cl = wn * 32 + nt * 16 + qr;
            float v = acc[mt][nt][r] * inv21 + biasv[nt];
            _Float16 h_, l_;
            splitf16(v * 2048.0f, &h_, &l_);
            int off;
            if (sect < 2)
              off = ((rl & 7) * 2 + (cl >> 6)) * 1024 + (rl >> 3) * 64 + (cl & 63);
            else  // granule XOR-swizzle: kills 16-way bank conflict
              off = (cl >> 6) * 8192 + (cl & 63) * 128 +
                    (((rl & 7) ^ (cl & 7)) * 16) + (rl >> 3);
            L[off] = pass ? l_ : h_;
          }
      __syncthreads();
      _Float16* dst = pass ? dstL : dstH;
      if (sect < 2) {
#pragma unroll
        for (int j = 0; j < 4; ++j) {
          int c = j * 512 + tid;                   // 16B chunk id, 0..2047
          int b = c >> 8, hh = (c >> 7) & 1;
          int tl = (c >> 3) & 15, dd = (c & 7) * 8;
          size_t gd = ((size_t)(b * 16 + hhBase + hh) << 16) +
                      (size_t)(t0 + tl) * 64 + dd;
          *(uint4*)(dst + gd) = *(const uint4*)(L + (size_t)c * 8);
        }
      } else {
#pragma unroll
        for (int j = 0; j < 2; ++j) {
          int c = j * 512 + tid;                   // 32B chunk id, 0..1023
          int hh = c >> 9, dd = (c >> 3) & 63, b = c & 7;
          size_t gd = ((size_t)(b * 16 + hhBase + hh) << 16) +
                      (size_t)dd * 1024 + t0;
          int gb = hh * 8192 + dd * 128 + ((b ^ (dd & 7)) * 16);
          *(uint4*)(dst + gd)     = *(const uint4*)(L + gb);
          *(uint4*)(dst + gd + 8) = *(const uint4*)(L + gb + 8);
        }
      }
    }
  } else {
#pragma unroll
    for (int mt = 0; mt < 4; ++mt)
#pragma unroll
      for (int nt = 0; nt < 2; ++nt)
#pragma unroll
        for (int r = 0; r < 4; ++r) {
          int grow = rowBase + wm * 64 + mt * 16 + lq * 4 + r;
          int col = colBase + wn * 32 + nt * 16 + qr;
          size_t o = (size_t)grow * N + col;
          out_f[o] = acc[mt][nt][r] * inv21 + biasv[nt] + res[o];
        }
  }
}

// ---------------------------------------------------------------------------
// flash attention, fp16x3, fixed-m softmax (P = exp(s-8), scores << 8).
// KVBLK=32, double-buffered K/V staged via global_load_lds.
// LDS 50176 B -> 3 blocks/CU. Explicit vmcnt(0) before barrier (replay-safe).
// s_setprio(1) around MFMA clusters (3 blocks/CU -> waves at distinct phases).
// ---------------------------------------------------------------------------
__global__ __launch_bounds__(256) void attn_f16x3(
    const _Float16* __restrict__ Qh, const _Float16* __restrict__ Ql,
    const _Float16* __restrict__ Kh, const _Float16* __restrict__ Kl,
    const _Float16* __restrict__ Vth, const _Float16* __restrict__ Vtl,
    _Float16* __restrict__ Ch, _Float16* __restrict__ Cl) {
  __shared__ __align__(16) char smem[50176];
  const int tid = threadIdx.x;
  const int lane = tid & 63, wave = tid >> 6;
  const int qr = lane & 15, lq = lane >> 4;
  // XCD remap: lin%8 = XCD -> contiguous bh range per XCD (K/V L2-resident)
  const int lin = blockIdx.y * 16 + blockIdx.x;
  const int xcd = lin & 7, k6 = lin >> 3;
  const int bh = xcd * 16 + (k6 >> 4);
  const int qt = k6 & 15;
  const size_t bo = (size_t)bh * 65536;
  const _Float16* Qhp = Qh + bo; const _Float16* Qlp = Ql + bo;
  const _Float16* Khp = Kh + bo; const _Float16* Klp = Kl + bo;
  const _Float16* Vhp = Vth + bo; const _Float16* Vlp = Vtl + bo;
  const int q0 = qt * 64 + wave * 16;

  f16x8 qhf[2], qlf[2];
#pragma unroll
  for (int kc = 0; kc < 2; ++kc) {
    size_t qo = (size_t)(q0 + qr) * 64 + kc*32 + lq*8;
    qhf[kc] = *(const f16x8*)(Qhp + qo);
    qlf[kc] = *(const f16x8*)(Qlp + qo);
  }
  f16x8 ones;
#pragma unroll
  for (int j = 0; j < 8; ++j) ones[j] = (_Float16)1.0f;

  f32x4 o[4], osum;
#pragma unroll
  for (int i = 0; i < 4; ++i) o[i] = fzero4();
  osum = fzero4();

  // staging source (pre-swizzled global addresses; LDS dest linear).
  const int krow = lane >> 3;                      // 0..7 within wave slice
  const int kswz = (lane & 7) ^ krow;
  const _Float16* gKH = Khp + (size_t)(wave*8 + krow) * 64 + kswz * 8;
  const _Float16* gKL = Klp + (size_t)(wave*8 + krow) * 64 + kswz * 8;
  const int vrow = lane >> 2;                      // 0..15 within wave slice
  const int vswz = (lane & 3) ^ (((lane >> 2) & 3) ^ ((lane >> 4) & 3));
  const _Float16* gVH = Vhp + (size_t)(wave*16 + vrow) * 1024 + vswz * 8;
  const _Float16* gVL = Vlp + (size_t)(wave*16 + vrow) * 1024 + vswz * 8;
  const unsigned ldsw = wave * 1024;               // wave-uniform slice base

#define STAGE(kb_, bufo_)                                                     \
  {                                                                           \
    gload16(gKH + (size_t)(kb_) * 2048, smem + (bufo_) + ldsw);               \
    gload16(gKL + (size_t)(kb_) * 2048, smem + 8192 + (bufo_) + ldsw);        \
    gload16(gVH + (size_t)(kb_) * 32, smem + 16384 + (bufo_) + ldsw);         \
    gload16(gVL + (size_t)(kb_) * 32, smem + 24576 + (bufo_) + ldsw);         \
  }

  STAGE(0, 0)
  const float sscale = 2.9802322387695312e-08f;  // 2^-22 * 0.125
  const int vfr = (qr & 3) ^ ((qr >> 2) & 3);    // V frag read swizzle
  char* ppw = smem + 32768 + wave * 4352;        // wave's PP slice

  for (int kb = 0; kb < 32; ++kb) {
    asm volatile("s_waitcnt vmcnt(0)" ::: "memory");  // drain DMA for tile kb
    __syncthreads();               // publish: tile kb resident in buf
    const int cur = (kb & 1) * 4096;
    if (kb + 1 < 32) STAGE(kb + 1, cur ^ 4096)   // flies during compute below

    // QK^T: S[q=lq*4+r][k=nt*16+qr]
    f32x4 s[2];
    __builtin_amdgcn_s_setprio(1);
#pragma unroll
    for (int nt = 0; nt < 2; ++nt) {
      f32x4 z = fzero4();
      const int r_ = nt*16 + qr;
#pragma unroll
      for (int kc = 0; kc < 2; ++kc) {
        int koff = cur + r_*128 + (((kc*4 + lq) ^ (r_ & 7)) * 16);
        f16x8 kh_ = *(const f16x8*)(smem + koff);
        f16x8 kl_ = *(const f16x8*)(smem + 8192 + koff);
        z = __builtin_amdgcn_mfma_f32_16x16x32_f16(qhf[kc], kh_, z, 0, 0, 0);
        z = __builtin_amdgcn_mfma_f32_16x16x32_f16(qhf[kc], kl_, z, 0, 0, 0);
        z = __builtin_amdgcn_mfma_f32_16x16x32_f16(qlf[kc], kh_, z, 0, 0, 0);
      }
      s[nt] = z;
    }
    __builtin_amdgcn_s_setprio(0);
    // P = exp(score - 8), scaled 2^11, split & packed -> per-wave PP
#pragma unroll
    for (int nt = 0; nt < 2; ++nt)
#pragma unroll
      for (int r = 0; r < 4; ++r) {
        float pv = __expf(__builtin_fmaf(s[nt][r], sscale, -8.0f)) * 2048.0f;
        _Float16 ph = (_Float16)pv;
        _Float16 pl = (_Float16)(pv - (float)ph);
        unsigned pk = (unsigned)__builtin_bit_cast(unsigned short, ph) |
                      ((unsigned)__builtin_bit_cast(unsigned short, pl) << 16);
        *(unsigned*)(ppw + ((lq*4 + r)*68 + nt*16 + qr) * 4) = pk;
      }
    // PP is per-wave: LDS-order fence only (rule #18 pattern)
    asm volatile("s_waitcnt lgkmcnt(0)" ::: "memory");
    __builtin_amdgcn_sched_barrier(0);
    // PV: A = P[q=qr][k=lq*8..+7]
    {
      const uint4* pp = (const uint4*)(ppw + (qr*68 + lq*8) * 4);
      uint4 pa = pp[0], pb = pp[1];
      uint4 hw, lw;
      hw.x = __builtin_amdgcn_perm(pa.y, pa.x, 0x05040100u);
      hw.y = __builtin_amdgcn_perm(pa.w, pa.z, 0x05040100u);
      hw.z = __builtin_amdgcn_perm(pb.y, pb.x, 0x05040100u);
      hw.w = __builtin_amdgcn_perm(pb.w, pb.z, 0x05040100u);
      lw.x = __builtin_amdgcn_perm(pa.y, pa.x, 0x07060302u);
      lw.y = __builtin_amdgcn_perm(pa.w, pa.z, 0x07060302u);
      lw.z = __builtin_amdgcn_perm(pb.y, pb.x, 0x07060302u);
      lw.w = __builtin_amdgcn_perm(pb.w, pb.z, 0x07060302u);
      f16x8 pah = __builtin_bit_cast(f16x8, hw);
      f16x8 pal = __builtin_bit_cast(f16x8, lw);
      __builtin_amdgcn_s_setprio(1);
#pragma unroll
      for (int dt = 0; dt < 4; ++dt) {
        int voff = cur + (dt*16 + qr)*64 + ((lq ^ vfr) * 16);
        f16x8 vh_ = *(const f16x8*)(smem + 16384 + voff);
        f16x8 vl_ = *(const f16x8*)(smem + 24576 + voff);
        o[dt] = __builtin_amdgcn_mfma_f32_16x16x32_f16(pah, vh_, o[dt], 0, 0, 0);
        o[dt] = __builtin_amdgcn_mfma_f32_16x16x32_f16(pah, vl_, o[dt], 0, 0, 0);
        o[dt] = __builtin_amdgcn_mfma_f32_16x16x32_f16(pal, vh_, o[dt], 0, 0, 0);
      }
      // row-sum of P via ones-fragment
      osum = __builtin_amdgcn_mfma_f32_16x16x32_f16(pah, ones, osum, 0, 0, 0);
      osum = __builtin_amdgcn_mfma_f32_16x16x32_f16(pal, ones, osum, 0, 0, 0);
      __builtin_amdgcn_s_setprio(0);
    }
  }
#undef STAGE
  const int b = bh >> 4, hh = bh & 15;
  // o = 2^22 * P.V ; osum = 2^11 * sum(P)  =>  o/osum = v_true * 2^11 (C scale)
#pragma unroll
  for (int dt = 0; dt < 4; ++dt)
#pragma unroll
    for (int r = 0; r < 4; ++r) {
      int tq = q0 + lq*4 + r;
      float v = o[dt][r] / osum[r];
      size_t idx = ((size_t)tq * 8 + b) * 1024 + hh*64 + dt*16 + qr;
      _Float16 h_, l_;
      splitf16(v, &h_, &l_);
      Ch[idx] = h_; Cl[idx] = l_;
    }
}

// ---------------------------------------------------------------------------
// LayerNorm over C=1024. one block per row. (LN2 path)
// ---------------------------------------------------------------------------
__global__ __launch_bounds__(256) void ln_kernel(
    const float* __restrict__ in, const float* __restrict__ g,
    const float* __restrict__ b, float* __restrict__ outf) {
  int row = blockIdx.x, tid = threadIdx.x;
  const float* xr = in + (size_t)row * 1024;
  float4 v = *(const float4*)(xr + tid*4);
  float s  = v.x + v.y + v.z + v.w;
  float sq = v.x*v.x + v.y*v.y + v.z*v.z + v.w*v.w;
#pragma unroll
  for (int off = 1; off < 64; off <<= 1) {
    s  += __shfl_xor(s, off, 64);
    sq += __shfl_xor(sq, off, 64);
  }
  __shared__ float red[8];
  int wv = tid >> 6, ln = tid & 63;
  if (ln == 0) { red[wv] = s; red[4 + wv] = sq; }
  __syncthreads();
  s  = red[0] + red[1] + red[2] + red[3];
  sq = red[4] + red[5] + red[6] + red[7];
  float mu   = s * 0.0009765625f;
  float var  = sq * 0.0009765625f - mu * mu;
  float rstd = 1.0f / sqrtf(var + 1e-5f);
  float4 gv = *(const float4*)(g + tid*4);
  float4 bv = *(const float4*)(b + tid*4);
  float4 o;
  o.x = (v.x - mu) * rstd * gv.x + bv.x;
  o.y = (v.y - mu) * rstd * gv.y + bv.y;
  o.z = (v.z - mu) * rstd * gv.z + bv.z;
  o.w = (v.w - mu) * rstd * gv.w + bv.w;
  *(float4*)(outf + (size_t)row * 1024 + tid*4) = o;
}

// ---------------------------------------------------------------------------
// LN1 + router fused: LayerNorm (fp32 out + bf16 out) then top-2 routing.
// Logit summation reproduces the old router_kernel BIT-EXACTLY:
// thread (w,l) holds router's (lane=l, j=w) float4 dot term; j-terms summed
// ascending ((d0+d1)+d2)+d3; then the identical 64-lane shuffle-xor tree.
// ---------------------------------------------------------------------------
__global__ __launch_bounds__(256) void ln_router_kernel(
    const float* __restrict__ in, const float* __restrict__ g,
    const float* __restrict__ b, float* __restrict__ outf,
    unsigned short* __restrict__ outbf,
    const float* __restrict__ rw, const float* __restrict__ rb,
    int* __restrict__ assign) {
  int row = blockIdx.x, tid = threadIdx.x;
  const float* xr = in + (size_t)row * 1024;
  float4 v = *(const float4*)(xr + tid*4);
  float s  = v.x + v.y + v.z + v.w;
  float sq = v.x*v.x + v.y*v.y + v.z*v.z + v.w*v.w;
#pragma unroll
  for (int off = 1; off < 64; off <<= 1) {
    s  += __shfl_xor(s, off, 64);
    sq += __shfl_xor(sq, off, 64);
  }
  __shared__ float red[8];
  __shared__ float D[4][8][64];
  int wv = tid >> 6, ln = tid & 63;
  if (ln == 0) { red[wv] = s; red[4 + wv] = sq; }
  __syncthreads();
  s  = red[0] + red[1] + red[2] + red[3];
  sq = red[4] + red[5] + red[6] + red[7];
  float mu   = s * 0.0009765625f;
  float var  = sq * 0.0009765625f - mu * mu;
  float rstd = 1.0f / sqrtf(var + 1e-5f);
  float4 gv = *(const float4*)(g + tid*4);
  float4 bv = *(const float4*)(b + tid*4);
  float4 o;
  o.x = (v.x - mu) * rstd * gv.x + bv.x;
  o.y = (v.y - mu) * rstd * gv.y + bv.y;
  o.z = (v.z - mu) * rstd * gv.z + bv.z;
  o.w = (v.w - mu) * rstd * gv.w + bv.w;
  *(float4*)(outf + (size_t)row * 1024 + tid*4) = o;
  ushort4 ob;
  ob.x = f2bf(o.x); ob.y = f2bf(o.y); ob.z = f2bf(o.z); ob.w = f2bf(o.w);
  *(ushort4*)(outbf + (size_t)row * 1024 + tid*4) = ob;
  // router partials: same dot expression as old router_kernel
#pragma unroll
  for (int e = 0; e < 8; ++e) {
    float4 wvv = *(const float4*)(rw + e*1024 + tid*4);
    D[wv][e][ln] = o.x*wvv.x + o.y*wvv.y + o.z*wvv.z + o.w*wvv.w;
  }
  __syncthreads();
  if (wv == 0) {
    float acc[8];
#pragma unroll
    for (int e = 0; e < 8; ++e) {
      float a0 = D[0][e][ln];        // j=0..3 ascending, left-assoc (router order)
      a0 += D[1][e][ln];
      a0 += D[2][e][ln];
      a0 += D[3][e][ln];
      acc[e] = a0;
    }
#pragma unroll
    for (int e = 0; e < 8; ++e) {
#pragma unroll
      for (int off = 1; off < 64; off <<= 1) acc[e] += __shfl_xor(acc[e], off, 64);
      acc[e] += rb[e];
    }
    if (ln == 0) {
      int i1 = 0; float v1 = acc[0];
#pragma unroll
      for (int e = 1; e < 8; ++e) if (acc[e] > v1) { v1 = acc[e]; i1 = e; }
      int i2 = -1; float v2 = -3.0e38f;
#pragma unroll
      for (int e = 0; e < 8; ++e) if (e != i1 && acc[e] > v2) { v2 = acc[e]; i2 = e; }
      assign[row] = (i1 > i2) ? i1 : i2;
    }
  }
}

// ---------------------------------------------------------------------------
// expert bucketing: parallel zero/count/scatter.
// ---------------------------------------------------------------------------
__global__ void zero_kernel(int* __restrict__ counts) {
  if (threadIdx.x < 16) counts[threadIdx.x] = 0;
}
__global__ void count_kernel(const int* __restrict__ assign, int* __restrict__ counts) {
  int i = blockIdx.x * 256 + threadIdx.x;
  if (i < 8192) atomicAdd(&counts[assign[i]], 1);
}
__global__ void scatter_kernel(const int* __restrict__ assign, int* __restrict__ counts,
                               int* __restrict__ list) {
  int i = blockIdx.x * 256 + threadIdx.x;
  if (i >= 8192) return;
  int a = assign[i];
  int base = 0;
  for (int e = 0; e < a; ++e) base += counts[e];
  int pos = atomicAdd(&counts[8 + a], 1);
  list[base + pos] = i;
}

// ---------------------------------------------------------------------------
// grouped MoE GEMM, bf16. 1-D grid 4096: expert = blk&7 (XCD-pinned),
// colb = (blk>>3)&7, rowb = blk>>6. 128x128 tile, BK=32, 512 threads/8 waves,
// 64x32 out per wave. global_load_lds double-buffer (vmcnt(0)+syncthreads).
// ---------------------------------------------------------------------------
template<int EPI>
__global__ __launch_bounds__(512) void gemm_moe(
    const unsigned short* __restrict__ A, const unsigned short* __restrict__ Bw,
    const float* __restrict__ bias, const float* __restrict__ res,
    float* __restrict__ out_f, unsigned short* __restrict__ out_bf,
    const int* __restrict__ list, const int* __restrict__ counts) {
  const int lin = blockIdx.x;
  const int e = lin & 7;                 // expert -> XCD pinned
  const int colb = (lin >> 3) & 7;
  const int rowb = lin >> 6;             // 0..63
  const int cnt = counts[e];
  if (rowb * 128 >= cnt) return;
  int base = 0;
  for (int i = 0; i < 8; ++i) if (i < e) base += counts[i];
  const unsigned short* Bp = Bw + (size_t)e * 1048576;
  const float* biasp = bias + e * 1024;

  __shared__ __align__(16) char smem[32768];  // 2 buf x (A 8KB + B 8KB)
  const int tid = threadIdx.x;
  const int lane = tid & 63, wave = tid >> 6;
  const int wm = wave >> 2, wn = wave & 3;     // 2 x 4 wave grid
  const int qr = lane & 15, lq = lane >> 4;
  const int rowBase = rowb * 128, colBase = colb * 128;

  const char *gA, *gB;
  {
    const int row = tid >> 2;
    const int gs = (tid & 3) ^ ((row >> 1) & 3);
    int grow = rowBase + row;
    int gi = (grow < cnt) ? grow : (cnt - 1);
    int arow = (EPI == 2) ? list[base + gi] : (base + gi);
    gA = (const char*)(A + (size_t)arow * 1024) + gs * 16;
    gB = (const char*)(Bp + (size_t)(colBase + row) * 1024) + gs * 16;
  }
  const unsigned ldsoA = wave * 1024;          // wave-uniform (lane*16 by HW)
  const unsigned ldsoB = 8192 + wave * 1024;

  f32x4 acc[4][2];
#pragma unroll
  for (int m = 0; m < 4; ++m)
#pragma unroll
    for (int n = 0; n < 2; ++n) acc[m][n] = fzero4();

  const int gfr = (qr >> 1) & 3;
  // prologue: stage tile 0 into buf 0
  gload16(gA, smem + ldsoA);
  gload16(gB, smem + ldsoB);
  gA += 64; gB += 64;

  for (int kt = 0; kt < 32; ++kt) {
    asm volatile("s_waitcnt vmcnt(0)" ::: "memory");  // explicit DMA drain
    __syncthreads();  // tile kt resident in buf[kt&1]
    const unsigned cur = (unsigned)(kt & 1) << 14;    // 16384
    const unsigned nxt = cur ^ 16384u;
    if (kt + 1 < 32) {
      gload16(gA, smem + nxt + ldsoA);
      gload16(gB, smem + nxt + ldsoB);
      gA += 64; gB += 64;
    }
    bf16x8 af[4], bf[2];
#pragma unroll
    for (int mt = 0; mt < 4; ++mt) {
      unsigned off = cur + (wm * 64 + mt * 16 + qr) * 64 + ((lq ^ gfr) * 16);
      af[mt] = *(const bf16x8*)(smem + off);
    }
#pragma unroll
    for (int nt = 0; nt < 2; ++nt) {
      unsigned off = cur + 8192 + (wn * 32 + nt * 16 + qr) * 64 + ((lq ^ gfr) * 16);
      bf[nt] = *(const bf16x8*)(smem + off);
    }
#pragma unroll
    for (int mt = 0; mt < 4; ++mt)
#pragma unroll
      for (int nt = 0; nt < 2; ++nt)
        acc[mt][nt] = __builtin_amdgcn_mfma_f32_16x16x32_bf16(
            af[mt], bf[nt], acc[mt][nt], 0, 0, 0);
  }

#pragma unroll
  for (int mt = 0; mt < 4; ++mt)
#pragma unroll
    for (int nt = 0; nt < 2; ++nt)
#pragma unroll
      for (int r = 0; r < 4; ++r) {
        int grow = rowBase + wm * 64 + mt * 16 + lq * 4 + r;
        int col  = colBase + wn * 32 + nt * 16 + qr;
        if (grow < cnt) {
          float v = acc[mt][nt][r] + biasp[col];
          if (EPI == 2) {
            float ge = 0.5f * v * (1.0f + erff(v * 0.70710678118654752f));
            out_bf[(size_t)(base + grow) * 1024 + col] = f2bf(ge);
          } else {
            int n = list[base + grow];
            size_t o2 = (size_t)n * 1024 + col;
            out_f[o2] = v + res[o2];
          }
        }
      }
}

// ---------------------------------------------------------------------------
extern "C" void kernel_launch(void* const* d_in, const int* in_sizes, int n_in,
                              void* d_out, int out_size, void* d_ws, size_t ws_size,
                              hipStream_t stream) {
  const float* x   = (const float*)d_in[0];
  const float* ipw = (const float*)d_in[1];
  const float* ipb = (const float*)d_in[2];
  const float* ow  = (const float*)d_in[3];
  const float* ob  = (const float*)d_in[4];
  const float* g1  = (const float*)d_in[5];
  const float* b1n = (const float*)d_in[6];
  const float* rw  = (const float*)d_in[7];
  const float* rb  = (const float*)d_in[8];
  const float* w1  = (const float*)d_in[9];
  const float* b1e = (const float*)d_in[10];
  const float* w2  = (const float*)d_in[11];
  const float* b2e = (const float*)d_in[12];
  const float* g2  = (const float*)d_in[13];
  const float* b2n = (const float*)d_in[14];

  char* ws = (char*)d_ws;
  const size_t MB = 1048576;
  _Float16* Xh  = (_Float16*)(ws + 0*MB);
  _Float16* Xl  = (_Float16*)(ws + 16*MB);
  _Float16* Wih = (_Float16*)(ws + 32*MB);
  _Float16* Wil = (_Float16*)(ws + 38*MB);
  _Float16* Woh = (_Float16*)(ws + 44*MB);
  _Float16* Wol = (_Float16*)(ws + 46*MB);
  unsigned short* w1b = (unsigned short*)(ws + 48*MB);
  unsigned short* w2b = (unsigned short*)(ws + 64*MB);
  _Float16* Qh  = (_Float16*)(ws + 80*MB);
  _Float16* Ql  = (_Float16*)(ws + 96*MB);
  _Float16* Kh  = (_Float16*)(ws + 112*MB);
  _Float16* Kl  = (_Float16*)(ws + 128*MB);
  _Float16* Vth = (_Float16*)(ws + 144*MB);
  _Float16* Vtl = (_Float16*)(ws + 160*MB);
  // overlays of dead regions:
  _Float16* Ch  = Xh;                                     // ctx hi (X dead)
  _Float16* Cl  = Xl;                                     // ctx lo
  float* tmp    = (float*)(ws + 80*MB);                   // over Q (dead post-attn)
  float* hbuf   = (float*)(ws + 112*MB);                  // over K
  unsigned short* hbf = (unsigned short*)(ws + 144*MB);   // over Vth
  unsigned short* he  = (unsigned short*)(ws + 160*MB);   // over Vtl
  int* assign = (int*)(ws + 176*MB);
  int* list   = (int*)(ws + 176*MB + 32768);
  int* counts = (int*)(ws + 176*MB + 65536);

  // 1) fused precision-split / cast
  prep_kernel<<<28672, 256, 0, stream>>>(x, Xh, Xl, ipw, Wih, Wil,
                                         ow, Woh, Wol, w1, w1b, w2, w2b);

  // 2) QKV projection (fp16x3), coalesced scatter epilogue
  gemm_f16x3<0><<<1536, 512, 0, stream>>>(
      Xh, Xl, Wih, Wil, ipb, 3072, 1024, nullptr, nullptr,
      Qh, Ql, Kh, Kl, Vth, Vtl);

  // 3) flash attention
  attn_f16x3<<<dim3(16, 128), 256, 0, stream>>>(Qh, Ql, Kh, Kl, Vth, Vtl, Ch, Cl);

  // 4) out-proj + residual(x) -> tmp
  gemm_f16x3<1><<<512, 512, 0, stream>>>(
      Ch, Cl, Woh, Wol, ob, 1024, 1024, tmp, x,
      nullptr, nullptr, nullptr, nullptr, nullptr, nullptr);

  // 5) LN1 + router fused -> h (fp32) + h_bf + assign
  ln_router_kernel<<<8192, 256, 0, stream>>>(tmp, g1, b1n, hbuf, hbf,
                                             rw, rb, assign);

  // 6) bucket tokens per expert (parallel)
  zero_kernel<<<1, 64, 0, stream>>>(counts);
  count_kernel<<<32, 256, 0, stream>>>(assign, counts);
  scatter_kernel<<<32, 256, 0, stream>>>(assign, counts, list);

  // 7) MoE FFN (bf16): he = gelu(h@w1^T+b1) ; tmp = h + (he@w2^T+b2)
  gemm_moe<2><<<4096, 512, 0, stream>>>(
      hbf, w1b, b1e, nullptr, nullptr, he, list, counts);
  gemm_moe<3><<<4096, 512, 0, stream>>>(
      he, w2b, b2e, hbuf, tmp, nullptr, list, counts);

  // 8) LN2 -> d_out
  ln_kernel<<<8192, 256, 0, stream>>>(tmp, g2, b2n, (float*)d_out);
}

// Round 15
// 665.406 us; speedup vs baseline: 1.0119x; 1.0119x over previous
//
#include <hip/hip_runtime.h>
#include <math.h>

// ---------------------------------------------------------------------------
// StandardMoELayer on MI355X.
// Precision: fp16x3 split-MFMA upstream of router; bf16 MFMA post-router.
// R15: attn QT=2 — each block processes TWO 64-row Q-tiles sharing one K/V
// staging stream (grid 2048->1024): staging per q-row halves, MFMA per
// barrier-pair doubles (26->52) — attacks the barrier-bound regime.
// K-frag LDS reads shared across tiles; PP reused sequentially (fenced).
// ---------------------------------------------------------------------------

typedef __attribute__((ext_vector_type(4))) float f32x4;
typedef __attribute__((ext_vector_type(8))) _Float16 f16x8;
typedef __attribute__((ext_vector_type(4))) _Float16 f16x4;
typedef __attribute__((ext_vector_type(8))) short bf16x8;

#define DEVI static __device__ __forceinline__

DEVI unsigned short f2bf(float f) {
  unsigned int u = __builtin_bit_cast(unsigned int, f);
  return (unsigned short)((u + 0x7fffu + ((u >> 16) & 1u)) >> 16);
}

DEVI f32x4 fzero4() { f32x4 z; z[0]=0.f; z[1]=0.f; z[2]=0.f; z[3]=0.f; return z; }

DEVI void splitf16(float v, _Float16* hi, _Float16* lo) {
  _Float16 h = (_Float16)v;
  *hi = h;
  *lo = (_Float16)(v - (float)h);
}

DEVI void gload16(const void* g, void* l) {
  __builtin_amdgcn_global_load_lds(
      (__attribute__((address_space(1))) void*)(g),
      (__attribute__((address_space(3))) void*)(l), 16, 0, 0);
}

// ---------------------------------------------------------------------------
// fused elementwise prep: x/ipw/ow fp16-split + w1/w2 bf16 cast, one launch
// ---------------------------------------------------------------------------
DEVI void do_split(const float* __restrict__ in, _Float16* __restrict__ oh,
                   _Float16* __restrict__ ol, float scale, int i) {
  float4 v = ((const float4*)in)[i];
  f16x4 hv, lv; _Float16 hh, ll;
  splitf16(v.x * scale, &hh, &ll); hv[0]=hh; lv[0]=ll;
  splitf16(v.y * scale, &hh, &ll); hv[1]=hh; lv[1]=ll;
  splitf16(v.z * scale, &hh, &ll); hv[2]=hh; lv[2]=ll;
  splitf16(v.w * scale, &hh, &ll); hv[3]=hh; lv[3]=ll;
  ((f16x4*)oh)[i] = hv;
  ((f16x4*)ol)[i] = lv;
}

DEVI void do_castbf(const float* __restrict__ in, unsigned short* __restrict__ o,
                    int i) {
  float4 v = ((const float4*)in)[i];
  ushort4 r;
  r.x = f2bf(v.x); r.y = f2bf(v.y); r.z = f2bf(v.z); r.w = f2bf(v.w);
  ((ushort4*)o)[i] = r;
}

__global__ void prep_kernel(const float* __restrict__ x,
                            _Float16* __restrict__ Xh, _Float16* __restrict__ Xl,
                            const float* __restrict__ ipw,
                            _Float16* __restrict__ Wih, _Float16* __restrict__ Wil,
                            const float* __restrict__ ow,
                            _Float16* __restrict__ Woh, _Float16* __restrict__ Wol,
                            const float* __restrict__ w1, unsigned short* __restrict__ w1b,
                            const float* __restrict__ w2, unsigned short* __restrict__ w2b) {
  int b = blockIdx.x, tid = threadIdx.x;
  if (b < 8192)        do_split(x,   Xh,  Xl,  2048.0f, b * 256 + tid);
  else if (b < 11264)  do_split(ipw, Wih, Wil, 1024.0f, (b - 8192) * 256 + tid);
  else if (b < 12288)  do_split(ow,  Woh, Wol, 1024.0f, (b - 11264) * 256 + tid);
  else if (b < 20480)  do_castbf(w1, w1b, (b - 12288) * 256 + tid);
  else                 do_castbf(w2, w2b, (b - 20480) * 256 + tid);
}

// ---------------------------------------------------------------------------
// fp16x3 GEMM: C[M=8192,N] = A[M,K] * W[N,K]^T  (A scaled 2^11, W scaled 2^10)
// 128x128 tile, BK=32, 512 threads = 8 waves (2x4), 64x32 out per wave.
// Double-buffered global_load_lds pipeline (vmcnt(0)+syncthreads, replay-safe)
// XCD-chunked grid. EPI 0: two-pass LDS-restage coalesced Q/K/V^T split-store.
// EPI 1: +bias +res -> fp32 out.
// ---------------------------------------------------------------------------
template<int EPI>
__global__ __launch_bounds__(512) void gemm_f16x3(
    const _Float16* __restrict__ Ah, const _Float16* __restrict__ Al,
    const _Float16* __restrict__ Bh, const _Float16* __restrict__ Bl,
    const float* __restrict__ bias, int N, int K,
    float* __restrict__ out_f, const float* __restrict__ res,
    _Float16* __restrict__ Qh, _Float16* __restrict__ Ql,
    _Float16* __restrict__ Kh, _Float16* __restrict__ Kl,
    _Float16* __restrict__ Vh, _Float16* __restrict__ Vl) {
  __shared__ __align__(16) char smem[65536];  // 2 buf x (4 arrays x 128 x 64 B)
  const int tid = threadIdx.x;
  const int lane = tid & 63, wave = tid >> 6;   // 0..7
  const int wm = wave >> 2, wn = wave & 3;      // 2 x 4 wave grid
  const int qr = lane & 15, lq = lane >> 4;

  // XCD-chunked block remap (nwg % 8 == 0 here)
  const int xcd = blockIdx.x & 7, idx = blockIdx.x >> 3;
  const int colsPerX = (N >> 7) >> 3;
  const int rowb = idx / colsPerX;
  const int colb = xcd * colsPerX + (idx - rowb * colsPerX);
  const int rowBase = rowb * 128, colBase = colb * 128;

  // staging: 1 granule-swizzled 16B chunk per array per thread.
  const char* gsrc[4];
  unsigned ldso[4];
  {
    const int row = tid >> 2;
    const int gs = (tid & 3) ^ ((row >> 1) & 3);
#pragma unroll
    for (int a = 0; a < 4; ++a) {
      const _Float16* basep = (a == 0) ? Ah : (a == 1) ? Al : (a == 2) ? Bh : Bl;
      int R0 = (a < 2) ? rowBase : colBase;
      gsrc[a] = (const char*)(basep + (size_t)(R0 + row) * K) + gs * 16;
      ldso[a] = a * 8192 + wave * 1024;  // wave-uniform
    }
  }

  f32x4 acc[4][2];
#pragma unroll
  for (int m = 0; m < 4; ++m)
#pragma unroll
    for (int n = 0; n < 2; ++n) acc[m][n] = fzero4();

  const int gfr = (qr >> 1) & 3;  // frag granule swizzle term
  const int NT = K >> 5;
  // prologue: stage tile 0 into buf 0
#pragma unroll
  for (int a = 0; a < 4; ++a) gload16(gsrc[a], smem + ldso[a]);
#pragma unroll
  for (int a = 0; a < 4; ++a) gsrc[a] += 64;

  for (int kt = 0; kt < NT; ++kt) {
    asm volatile("s_waitcnt vmcnt(0)" ::: "memory");  // explicit DMA drain
    __syncthreads();  // tile kt resident in buf[kt&1]
    const unsigned cur = (unsigned)(kt & 1) << 15;
    const unsigned nxt = cur ^ 32768u;
    if (kt + 1 < NT) {
#pragma unroll
      for (int a = 0; a < 4; ++a) gload16(gsrc[a], smem + nxt + ldso[a]);
#pragma unroll
      for (int a = 0; a < 4; ++a) gsrc[a] += 64;
    }
    f16x8 ahf[4], alf[4], bhf[2], blf[2];
#pragma unroll
    for (int mt = 0; mt < 4; ++mt) {
      unsigned off = cur + (wm * 64 + mt * 16 + qr) * 64 + ((lq ^ gfr) * 16);
      ahf[mt] = *(const f16x8*)(smem + off);
      alf[mt] = *(const f16x8*)(smem + 8192 + off);
    }
#pragma unroll
    for (int nt = 0; nt < 2; ++nt) {
      unsigned off = cur + (wn * 32 + nt * 16 + qr) * 64 + ((lq ^ gfr) * 16);
      bhf[nt] = *(const f16x8*)(smem + 16384 + off);
      blf[nt] = *(const f16x8*)(smem + 24576 + off);
    }
#pragma unroll
    for (int mt = 0; mt < 4; ++mt)
#pragma unroll
      for (int nt = 0; nt < 2; ++nt) {
        f32x4 c = acc[mt][nt];
        c = __builtin_amdgcn_mfma_f32_16x16x32_f16(ahf[mt], bhf[nt], c, 0, 0, 0);
        c = __builtin_amdgcn_mfma_f32_16x16x32_f16(ahf[mt], blf[nt], c, 0, 0, 0);
        c = __builtin_amdgcn_mfma_f32_16x16x32_f16(alf[mt], bhf[nt], c, 0, 0, 0);
        acc[mt][nt] = c;
      }
  }

  const float inv21 = 1.0f / 2097152.0f;  // 2^-21
  float biasv[2];
#pragma unroll
  for (int nt = 0; nt < 2; ++nt) biasv[nt] = bias[colBase + wn * 32 + nt * 16 + qr];

  if (EPI == 0) {
    __syncthreads();  // staging LDS reusable now
    const int sect = colBase >> 10;                // 0=Q 1=K 2=V (block-uniform)
    const int hhBase = (colBase & 1023) >> 6;
    const int t0 = rowBase >> 3;
    _Float16* L = (_Float16*)smem;                 // 16384 fp16 = 32 KB
    _Float16* dstH = (sect == 0) ? Qh : (sect == 1) ? Kh : Vh;
    _Float16* dstL = (sect == 0) ? Ql : (sect == 1) ? Kl : Vl;
#pragma unroll
    for (int pass = 0; pass < 2; ++pass) {
      if (pass) __syncthreads();
      // scatter acc into LDS in output-linear layout
#pragma unroll
      for (int mt = 0; mt < 4; ++mt)
#pragma unroll
        for (int nt = 0; nt < 2; ++nt)
#pragma unroll
          for (int r = 0; r < 4; ++r) {
            int rl = wm * 64 + mt * 16 + lq * 4 + r;
            int cl = wn * 32 + nt * 16 + qr;
            float v = acc[mt][nt][r] * inv21 + biasv[nt];
            _Float16 h_, l_;
            splitf16(v * 2048.0f, &h_, &l_);
            int off;
            if (sect < 2)
              off = ((rl & 7) * 2 + (cl >> 6)) * 1024 + (rl >> 3) * 64 + (cl & 63);
            else  // granule XOR-swizzle: kills 16-way bank conflict
              off = (cl >> 6) * 8192 + (cl & 63) * 128 +
                    (((rl & 7) ^ (cl & 7)) * 16) + (rl >> 3);
            L[off] = pass ? l_ : h_;
          }
      __syncthreads();
      _Float16* dst = pass ? dstL : dstH;
      if (sect < 2) {
#pragma unroll
        for (int j = 0; j < 4; ++j) {
          int c = j * 512 + tid;                   // 16B chunk id, 0..2047
          int b = c >> 8, hh = (c >> 7) & 1;
          int tl = (c >> 3) & 15, dd = (c & 7) * 8;
          size_t gd = ((size_t)(b * 16 + hhBase + hh) << 16) +
                      (size_t)(t0 + tl) * 64 + dd;
          *(uint4*)(dst + gd) = *(const uint4*)(L + (size_t)c * 8);
        }
      } else {
#pragma unroll
        for (int j = 0; j < 2; ++j) {
          int c = j * 512 + tid;                   // 32B chunk id, 0..1023
          int hh = c >> 9, dd = (c >> 3) & 63, b = c & 7;
          size_t gd = ((size_t)(b * 16 + hhBase + hh) << 16) +
                      (size_t)dd * 1024 + t0;
          int gb = hh * 8192 + dd * 128 + ((b ^ (dd & 7)) * 16);
          *(uint4*)(dst + gd)     = *(const uint4*)(L + gb);
          *(uint4*)(dst + gd + 8) = *(const uint4*)(L + gb + 8);
        }
      }
    }
  } else {
#pragma unroll
    for (int mt = 0; mt < 4; ++mt)
#pragma unroll
      for (int nt = 0; nt < 2; ++nt)
#pragma unroll
        for (int r = 0; r < 4; ++r) {
          int grow = rowBase + wm * 64 + mt * 16 + lq * 4 + r;
          int col = colBase + wn * 32 + nt * 16 + qr;
          size_t o = (size_t)grow * N + col;
          out_f[o] = acc[mt][nt][r] * inv21 + biasv[nt] + res[o];
        }
  }
}

// ---------------------------------------------------------------------------
// flash attention, fp16x3, fixed-m softmax (P = exp(s-8), scores << 8).
// QT=2: two 64-row Q-tiles per block share one K/V staging stream.
// KVBLK=32, double-buffered K/V via global_load_lds; vmcnt(0)+barrier.
// LDS 50176 B -> 3 blocks/CU. grid 1024 XCD-remapped.
// ---------------------------------------------------------------------------
__global__ __launch_bounds__(256) void attn_f16x3(
    const _Float16* __restrict__ Qh, const _Float16* __restrict__ Ql,
    const _Float16* __restrict__ Kh, const _Float16* __restrict__ Kl,
    const _Float16* __restrict__ Vth, const _Float16* __restrict__ Vtl,
    _Float16* __restrict__ Ch, _Float16* __restrict__ Cl) {
  __shared__ __align__(16) char smem[50176];
  const int tid = threadIdx.x;
  const int lane = tid & 63, wave = tid >> 6;
  const int qr = lane & 15, lq = lane >> 4;
  // XCD remap: lin%8 = XCD -> contiguous bh range per XCD (K/V L2-resident)
  const int lin = blockIdx.y * 16 + blockIdx.x;
  const int xcd = lin & 7, k6 = lin >> 3;        // k6: 0..127
  const int bh = xcd * 16 + (k6 >> 3);
  const int qp = k6 & 7;                         // q-pair tile, 128 rows
  const size_t bo = (size_t)bh * 65536;
  const _Float16* Qhp = Qh + bo; const _Float16* Qlp = Ql + bo;
  const _Float16* Khp = Kh + bo; const _Float16* Klp = Kl + bo;
  const _Float16* Vhp = Vth + bo; const _Float16* Vlp = Vtl + bo;
  const int q0 = qp * 128 + wave * 16;           // tile t adds t*64

  f16x8 qhf[2][2], qlf[2][2];                    // [tile][kc]
#pragma unroll
  for (int t = 0; t < 2; ++t)
#pragma unroll
    for (int kc = 0; kc < 2; ++kc) {
      size_t qo = (size_t)(q0 + t*64 + qr) * 64 + kc*32 + lq*8;
      qhf[t][kc] = *(const f16x8*)(Qhp + qo);
      qlf[t][kc] = *(const f16x8*)(Qlp + qo);
    }
  f16x8 ones;
#pragma unroll
  for (int j = 0; j < 8; ++j) ones[j] = (_Float16)1.0f;

  f32x4 o0[4], o1[4], osum0, osum1;
#pragma unroll
  for (int i = 0; i < 4; ++i) { o0[i] = fzero4(); o1[i] = fzero4(); }
  osum0 = fzero4(); osum1 = fzero4();

  // staging source (pre-swizzled global addresses; LDS dest linear).
  const int krow = lane >> 3;                      // 0..7 within wave slice
  const int kswz = (lane & 7) ^ krow;
  const _Float16* gKH = Khp + (size_t)(wave*8 + krow) * 64 + kswz * 8;
  const _Float16* gKL = Klp + (size_t)(wave*8 + krow) * 64 + kswz * 8;
  const int vrow = lane >> 2;                      // 0..15 within wave slice
  const int vswz = (lane & 3) ^ (((lane >> 2) & 3) ^ ((lane >> 4) & 3));
  const _Float16* gVH = Vhp + (size_t)(wave*16 + vrow) * 1024 + vswz * 8;
  const _Float16* gVL = Vlp + (size_t)(wave*16 + vrow) * 1024 + vswz * 8;
  const unsigned ldsw = wave * 1024;               // wave-uniform slice base

#define STAGE(kb_, bufo_)                                                     \
  {                                                                           \
    gload16(gKH + (size_t)(kb_) * 2048, smem + (bufo_) + ldsw);               \
    gload16(gKL + (size_t)(kb_) * 2048, smem + 8192 + (bufo_) + ldsw);        \
    gload16(gVH + (size_t)(kb_) * 32, smem + 16384 + (bufo_) + ldsw);         \
    gload16(gVL + (size_t)(kb_) * 32, smem + 24576 + (bufo_) + ldsw);         \
  }

// pack P for one tile into PP, fence, then PV into (o_, osum_)
#define SM_PV(sarr, o_, osum_)                                                \
  {                                                                           \
    _Pragma("unroll")                                                         \
    for (int nt = 0; nt < 2; ++nt)                                            \
      _Pragma("unroll")                                                       \
      for (int r = 0; r < 4; ++r) {                                           \
        float pv = __expf(__builtin_fmaf(sarr[nt][r], sscale, -8.0f)) * 2048.0f; \
        _Float16 ph = (_Float16)pv;                                           \
        _Float16 pl = (_Float16)(pv - (float)ph);                             \
        unsigned pk = (unsigned)__builtin_bit_cast(unsigned short, ph) |      \
                      ((unsigned)__builtin_bit_cast(unsigned short, pl) << 16); \
        *(unsigned*)(ppw + ((lq*4 + r)*68 + nt*16 + qr) * 4) = pk;            \
      }                                                                       \
    asm volatile("s_waitcnt lgkmcnt(0)" ::: "memory");                        \
    __builtin_amdgcn_sched_barrier(0);                                        \
    {                                                                         \
      const uint4* pp = (const uint4*)(ppw + (qr*68 + lq*8) * 4);             \
      uint4 pa = pp[0], pb = pp[1];                                           \
      uint4 hw, lw;                                                           \
      hw.x = __builtin_amdgcn_perm(pa.y, pa.x, 0x05040100u);                  \
      hw.y = __builtin_amdgcn_perm(pa.w, pa.z, 0x05040100u);                  \
      hw.z = __builtin_amdgcn_perm(pb.y, pb.x, 0x05040100u);                  \
      hw.w = __builtin_amdgcn_perm(pb.w, pb.z, 0x05040100u);                  \
      lw.x = __builtin_amdgcn_perm(pa.y, pa.x, 0x07060302u);                  \
      lw.y = __builtin_amdgcn_perm(pa.w, pa.z, 0x07060302u);                  \
      lw.z = __builtin_amdgcn_perm(pb.y, pb.x, 0x07060302u);                  \
      lw.w = __builtin_amdgcn_perm(pb.w, pb.z, 0x07060302u);                  \
      f16x8 pah = __builtin_bit_cast(f16x8, hw);                              \
      f16x8 pal = __builtin_bit_cast(f16x8, lw);                              \
      __builtin_amdgcn_s_setprio(1);                                          \
      _Pragma("unroll")                                                       \
      for (int dt = 0; dt < 4; ++dt) {                                        \
        int voff = cur + (dt*16 + qr)*64 + ((lq ^ vfr) * 16);                 \
        f16x8 vh_ = *(const f16x8*)(smem + 16384 + voff);                     \
        f16x8 vl_ = *(const f16x8*)(smem + 24576 + voff);                     \
        o_[dt] = __builtin_amdgcn_mfma_f32_16x16x32_f16(pah, vh_, o_[dt], 0, 0, 0); \
        o_[dt] = __builtin_amdgcn_mfma_f32_16x16x32_f16(pah, vl_, o_[dt], 0, 0, 0); \
        o_[dt] = __builtin_amdgcn_mfma_f32_16x16x32_f16(pal, vh_, o_[dt], 0, 0, 0); \
      }                                                                       \
      osum_ = __builtin_amdgcn_mfma_f32_16x16x32_f16(pah, ones, osum_, 0, 0, 0); \
      osum_ = __builtin_amdgcn_mfma_f32_16x16x32_f16(pal, ones, osum_, 0, 0, 0); \
      __builtin_amdgcn_s_setprio(0);                                          \
    }                                                                         \
  }

  STAGE(0, 0)
  const float sscale = 2.9802322387695312e-08f;  // 2^-22 * 0.125
  const int vfr = (qr & 3) ^ ((qr >> 2) & 3);    // V frag read swizzle
  char* ppw = smem + 32768 + wave * 4352;        // wave's PP slice

  for (int kb = 0; kb < 32; ++kb) {
    asm volatile("s_waitcnt vmcnt(0)" ::: "memory");  // drain DMA for tile kb
    __syncthreads();               // publish: tile kb resident in buf
    const int cur = (kb & 1) * 4096;
    if (kb + 1 < 32) STAGE(kb + 1, cur ^ 4096)   // flies during compute below

    // QK^T both tiles, sharing K fragment loads
    f32x4 s0[2], s1[2];
    __builtin_amdgcn_s_setprio(1);
#pragma unroll
    for (int nt = 0; nt < 2; ++nt) {
      f32x4 z0 = fzero4(), z1 = fzero4();
      const int r_ = nt*16 + qr;
#pragma unroll
      for (int kc = 0; kc < 2; ++kc) {
        int koff = cur + r_*128 + (((kc*4 + lq) ^ (r_ & 7)) * 16);
        f16x8 kh_ = *(const f16x8*)(smem + koff);
        f16x8 kl_ = *(const f16x8*)(smem + 8192 + koff);
        z0 = __builtin_amdgcn_mfma_f32_16x16x32_f16(qhf[0][kc], kh_, z0, 0, 0, 0);
        z0 = __builtin_amdgcn_mfma_f32_16x16x32_f16(qhf[0][kc], kl_, z0, 0, 0, 0);
        z0 = __builtin_amdgcn_mfma_f32_16x16x32_f16(qlf[0][kc], kh_, z0, 0, 0, 0);
        z1 = __builtin_amdgcn_mfma_f32_16x16x32_f16(qhf[1][kc], kh_, z1, 0, 0, 0);
        z1 = __builtin_amdgcn_mfma_f32_16x16x32_f16(qhf[1][kc], kl_, z1, 0, 0, 0);
        z1 = __builtin_amdgcn_mfma_f32_16x16x32_f16(qlf[1][kc], kh_, z1, 0, 0, 0);
      }
      s0[nt] = z0; s1[nt] = z1;
    }
    __builtin_amdgcn_s_setprio(0);
    SM_PV(s0, o0, osum0)
    SM_PV(s1, o1, osum1)
  }
#undef STAGE
#undef SM_PV
  const int b = bh >> 4, hh = bh & 15;
  // o = 2^22 * P.V ; osum = 2^11 * sum(P)  =>  o/osum = v_true * 2^11 (C scale)
#pragma unroll
  for (int t = 0; t < 2; ++t) {
    f32x4* op = t ? o1 : o0;
    f32x4 osum = t ? osum1 : osum0;
#pragma unroll
    for (int dt = 0; dt < 4; ++dt)
#pragma unroll
      for (int r = 0; r < 4; ++r) {
        int tq = q0 + t*64 + lq*4 + r;
        float v = op[dt][r] / osum[r];
        size_t idx = ((size_t)tq * 8 + b) * 1024 + hh*64 + dt*16 + qr;
        _Float16 h_, l_;
        splitf16(v, &h_, &l_);
        Ch[idx] = h_; Cl[idx] = l_;
      }
  }
}

// ---------------------------------------------------------------------------
// LayerNorm over C=1024. one block per row. (LN2 path)
// ---------------------------------------------------------------------------
__global__ __launch_bounds__(256) void ln_kernel(
    const float* __restrict__ in, const float* __restrict__ g,
    const float* __restrict__ b, float* __restrict__ outf) {
  int row = blockIdx.x, tid = threadIdx.x;
  const float* xr = in + (size_t)row * 1024;
  float4 v = *(const float4*)(xr + tid*4);
  float s  = v.x + v.y + v.z + v.w;
  float sq = v.x*v.x + v.y*v.y + v.z*v.z + v.w*v.w;
#pragma unroll
  for (int off = 1; off < 64; off <<= 1) {
    s  += __shfl_xor(s, off, 64);
    sq += __shfl_xor(sq, off, 64);
  }
  __shared__ float red[8];
  int wv = tid >> 6, ln = tid & 63;
  if (ln == 0) { red[wv] = s; red[4 + wv] = sq; }
  __syncthreads();
  s  = red[0] + red[1] + red[2] + red[3];
  sq = red[4] + red[5] + red[6] + red[7];
  float mu   = s * 0.0009765625f;
  float var  = sq * 0.0009765625f - mu * mu;
  float rstd = 1.0f / sqrtf(var + 1e-5f);
  float4 gv = *(const float4*)(g + tid*4);
  float4 bv = *(const float4*)(b + tid*4);
  float4 o;
  o.x = (v.x - mu) * rstd * gv.x + bv.x;
  o.y = (v.y - mu) * rstd * gv.y + bv.y;
  o.z = (v.z - mu) * rstd * gv.z + bv.z;
  o.w = (v.w - mu) * rstd * gv.w + bv.w;
  *(float4*)(outf + (size_t)row * 1024 + tid*4) = o;
}

// ---------------------------------------------------------------------------
// LN1 + router fused (bit-exact router summation, see R14 notes).
// ---------------------------------------------------------------------------
__global__ __launch_bounds__(256) void ln_router_kernel(
    const float* __restrict__ in, const float* __restrict__ g,
    const float* __restrict__ b, float* __restrict__ outf,
    unsigned short* __restrict__ outbf,
    const float* __restrict__ rw, const float* __restrict__ rb,
    int* __restrict__ assign) {
  int row = blockIdx.x, tid = threadIdx.x;
  const float* xr = in + (size_t)row * 1024;
  float4 v = *(const float4*)(xr + tid*4);
  float s  = v.x + v.y + v.z + v.w;
  float sq = v.x*v.x + v.y*v.y + v.z*v.z + v.w*v.w;
#pragma unroll
  for (int off = 1; off < 64; off <<= 1) {
    s  += __shfl_xor(s, off, 64);
    sq += __shfl_xor(sq, off, 64);
  }
  __shared__ float red[8];
  __shared__ float D[4][8][64];
  int wv = tid >> 6, ln = tid & 63;
  if (ln == 0) { red[wv] = s; red[4 + wv] = sq; }
  __syncthreads();
  s  = red[0] + red[1] + red[2] + red[3];
  sq = red[4] + red[5] + red[6] + red[7];
  float mu   = s * 0.0009765625f;
  float var  = sq * 0.0009765625f - mu * mu;
  float rstd = 1.0f / sqrtf(var + 1e-5f);
  float4 gv = *(const float4*)(g + tid*4);
  float4 bv = *(const float4*)(b + tid*4);
  float4 o;
  o.x = (v.x - mu) * rstd * gv.x + bv.x;
  o.y = (v.y - mu) * rstd * gv.y + bv.y;
  o.z = (v.z - mu) * rstd * gv.z + bv.z;
  o.w = (v.w - mu) * rstd * gv.w + bv.w;
  *(float4*)(outf + (size_t)row * 1024 + tid*4) = o;
  ushort4 ob;
  ob.x = f2bf(o.x); ob.y = f2bf(o.y); ob.z = f2bf(o.z); ob.w = f2bf(o.w);
  *(ushort4*)(outbf + (size_t)row * 1024 + tid*4) = ob;
  // router partials: same dot expression as old router_kernel
#pragma unroll
  for (int e = 0; e < 8; ++e) {
    float4 wvv = *(const float4*)(rw + e*1024 + tid*4);
    D[wv][e][ln] = o.x*wvv.x + o.y*wvv.y + o.z*wvv.z + o.w*wvv.w;
  }
  __syncthreads();
  if (wv == 0) {
    float acc[8];
#pragma unroll
    for (int e = 0; e < 8; ++e) {
      float a0 = D[0][e][ln];        // j=0..3 ascending, left-assoc (router order)
      a0 += D[1][e][ln];
      a0 += D[2][e][ln];
      a0 += D[3][e][ln];
      acc[e] = a0;
    }
#pragma unroll
    for (int e = 0; e < 8; ++e) {
#pragma unroll
      for (int off = 1; off < 64; off <<= 1) acc[e] += __shfl_xor(acc[e], off, 64);
      acc[e] += rb[e];
    }
    if (ln == 0) {
      int i1 = 0; float v1 = acc[0];
#pragma unroll
      for (int e = 1; e < 8; ++e) if (acc[e] > v1) { v1 = acc[e]; i1 = e; }
      int i2 = -1; float v2 = -3.0e38f;
#pragma unroll
      for (int e = 0; e < 8; ++e) if (e != i1 && acc[e] > v2) { v2 = acc[e]; i2 = e; }
      assign[row] = (i1 > i2) ? i1 : i2;
    }
  }
}

// ---------------------------------------------------------------------------
// expert bucketing: parallel zero/count/scatter.
// ---------------------------------------------------------------------------
__global__ void zero_kernel(int* __restrict__ counts) {
  if (threadIdx.x < 16) counts[threadIdx.x] = 0;
}
__global__ void count_kernel(const int* __restrict__ assign, int* __restrict__ counts) {
  int i = blockIdx.x * 256 + threadIdx.x;
  if (i < 8192) atomicAdd(&counts[assign[i]], 1);
}
__global__ void scatter_kernel(const int* __restrict__ assign, int* __restrict__ counts,
                               int* __restrict__ list) {
  int i = blockIdx.x * 256 + threadIdx.x;
  if (i >= 8192) return;
  int a = assign[i];
  int base = 0;
  for (int e = 0; e < a; ++e) base += counts[e];
  int pos = atomicAdd(&counts[8 + a], 1);
  list[base + pos] = i;
}

// ---------------------------------------------------------------------------
// grouped MoE GEMM, bf16. 1-D grid 4096: expert = blk&7 (XCD-pinned),
// colb = (blk>>3)&7, rowb = blk>>6. 128x128 tile, BK=32, 512 threads/8 waves,
// 64x32 out per wave. global_load_lds double-buffer (vmcnt(0)+syncthreads).
// ---------------------------------------------------------------------------
template<int EPI>
__global__ __launch_bounds__(512) void gemm_moe(
    const unsigned short* __restrict__ A, const unsigned short* __restrict__ Bw,
    const float* __restrict__ bias, const float* __restrict__ res,
    float* __restrict__ out_f, unsigned short* __restrict__ out_bf,
    const int* __restrict__ list, const int* __restrict__ counts) {
  const int lin = blockIdx.x;
  const int e = lin & 7;                 // expert -> XCD pinned
  const int colb = (lin >> 3) & 7;
  const int rowb = lin >> 6;             // 0..63
  const int cnt = counts[e];
  if (rowb * 128 >= cnt) return;
  int base = 0;
  for (int i = 0; i < 8; ++i) if (i < e) base += counts[i];
  const unsigned short* Bp = Bw + (size_t)e * 1048576;
  const float* biasp = bias + e * 1024;

  __shared__ __align__(16) char smem[32768];  // 2 buf x (A 8KB + B 8KB)
  const int tid = threadIdx.x;
  const int lane = tid & 63, wave = tid >> 6;
  const int wm = wave >> 2, wn = wave & 3;     // 2 x 4 wave grid
  const int qr = lane & 15, lq = lane >> 4;
  const int rowBase = rowb * 128, colBase = colb * 128;

  const char *gA, *gB;
  {
    const int row = tid >> 2;
    const int gs = (tid & 3) ^ ((row >> 1) & 3);
    int grow = rowBase + row;
    int gi = (grow < cnt) ? grow : (cnt - 1);
    int arow = (EPI == 2) ? list[base + gi] : (base + gi);
    gA = (const char*)(A + (size_t)arow * 1024) + gs * 16;
    gB = (const char*)(Bp + (size_t)(colBase + row) * 1024) + gs * 16;
  }
  const unsigned ldsoA = wave * 1024;          // wave-uniform (lane*16 by HW)
  const unsigned ldsoB = 8192 + wave * 1024;

  f32x4 acc[4][2];
#pragma unroll
  for (int m = 0; m < 4; ++m)
#pragma unroll
    for (int n = 0; n < 2; ++n) acc[m][n] = fzero4();

  const int gfr = (qr >> 1) & 3;
  // prologue: stage tile 0 into buf 0
  gload16(gA, smem + ldsoA);
  gload16(gB, smem + ldsoB);
  gA += 64; gB += 64;

  for (int kt = 0; kt < 32; ++kt) {
    asm volatile("s_waitcnt vmcnt(0)" ::: "memory");  // explicit DMA drain
    __syncthreads();  // tile kt resident in buf[kt&1]
    const unsigned cur = (unsigned)(kt & 1) << 14;    // 16384
    const unsigned nxt = cur ^ 16384u;
    if (kt + 1 < 32) {
      gload16(gA, smem + nxt + ldsoA);
      gload16(gB, smem + nxt + ldsoB);
      gA += 64; gB += 64;
    }
    bf16x8 af[4], bf[2];
#pragma unroll
    for (int mt = 0; mt < 4; ++mt) {
      unsigned off = cur + (wm * 64 + mt * 16 + qr) * 64 + ((lq ^ gfr) * 16);
      af[mt] = *(const bf16x8*)(smem + off);
    }
#pragma unroll
    for (int nt = 0; nt < 2; ++nt) {
      unsigned off = cur + 8192 + (wn * 32 + nt * 16 + qr) * 64 + ((lq ^ gfr) * 16);
      bf[nt] = *(const bf16x8*)(smem + off);
    }
#pragma unroll
    for (int mt = 0; mt < 4; ++mt)
#pragma unroll
      for (int nt = 0; nt < 2; ++nt)
        acc[mt][nt] = __builtin_amdgcn_mfma_f32_16x16x32_bf16(
            af[mt], bf[nt], acc[mt][nt], 0, 0, 0);
  }

#pragma unroll
  for (int mt = 0; mt < 4; ++mt)
#pragma unroll
    for (int nt = 0; nt < 2; ++nt)
#pragma unroll
      for (int r = 0; r < 4; ++r) {
        int grow = rowBase + wm * 64 + mt * 16 + lq * 4 + r;
        int col  = colBase + wn * 32 + nt * 16 + qr;
        if (grow < cnt) {
          float v = acc[mt][nt][r] + biasp[col];
          if (EPI == 2) {
            float ge = 0.5f * v * (1.0f + erff(v * 0.70710678118654752f));
            out_bf[(size_t)(base + grow) * 1024 + col] = f2bf(ge);
          } else {
            int n = list[base + grow];
            size_t o2 = (size_t)n * 1024 + col;
            out_f[o2] = v + res[o2];
          }
        }
      }
}

// ---------------------------------------------------------------------------
extern "C" void kernel_launch(void* const* d_in, const int* in_sizes, int n_in,
                              void* d_out, int out_size, void* d_ws, size_t ws_size,
                              hipStream_t stream) {
  const float* x   = (const float*)d_in[0];
  const float* ipw = (const float*)d_in[1];
  const float* ipb = (const float*)d_in[2];
  const float* ow  = (const float*)d_in[3];
  const float* ob  = (const float*)d_in[4];
  const float* g1  = (const float*)d_in[5];
  const float* b1n = (const float*)d_in[6];
  const float* rw  = (const float*)d_in[7];
  const float* rb  = (const float*)d_in[8];
  const float* w1  = (const float*)d_in[9];
  const float* b1e = (const float*)d_in[10];
  const float* w2  = (const float*)d_in[11];
  const float* b2e = (const float*)d_in[12];
  const float* g2  = (const float*)d_in[13];
  const float* b2n = (const float*)d_in[14];

  char* ws = (char*)d_ws;
  const size_t MB = 1048576;
  _Float16* Xh  = (_Float16*)(ws + 0*MB);
  _Float16* Xl  = (_Float16*)(ws + 16*MB);
  _Float16* Wih = (_Float16*)(ws + 32*MB);
  _Float16* Wil = (_Float16*)(ws + 38*MB);
  _Float16* Woh = (_Float16*)(ws + 44*MB);
  _Float16* Wol = (_Float16*)(ws + 46*MB);
  unsigned short* w1b = (unsigned short*)(ws + 48*MB);
  unsigned short* w2b = (unsigned short*)(ws + 64*MB);
  _Float16* Qh  = (_Float16*)(ws + 80*MB);
  _Float16* Ql  = (_Float16*)(ws + 96*MB);
  _Float16* Kh  = (_Float16*)(ws + 112*MB);
  _Float16* Kl  = (_Float16*)(ws + 128*MB);
  _Float16* Vth = (_Float16*)(ws + 144*MB);
  _Float16* Vtl = (_Float16*)(ws + 160*MB);
  // overlays of dead regions:
  _Float16* Ch  = Xh;                                     // ctx hi (X dead)
  _Float16* Cl  = Xl;                                     // ctx lo
  float* tmp    = (float*)(ws + 80*MB);                   // over Q (dead post-attn)
  float* hbuf   = (float*)(ws + 112*MB);                  // over K
  unsigned short* hbf = (unsigned short*)(ws + 144*MB);   // over Vth
  unsigned short* he  = (unsigned short*)(ws + 160*MB);   // over Vtl
  int* assign = (int*)(ws + 176*MB);
  int* list   = (int*)(ws + 176*MB + 32768);
  int* counts = (int*)(ws + 176*MB + 65536);

  // 1) fused precision-split / cast
  prep_kernel<<<28672, 256, 0, stream>>>(x, Xh, Xl, ipw, Wih, Wil,
                                         ow, Woh, Wol, w1, w1b, w2, w2b);

  // 2) QKV projection (fp16x3), coalesced scatter epilogue
  gemm_f16x3<0><<<1536, 512, 0, stream>>>(
      Xh, Xl, Wih, Wil, ipb, 3072, 1024, nullptr, nullptr,
      Qh, Ql, Kh, Kl, Vth, Vtl);

  // 3) flash attention (QT=2: 1024 blocks)
  attn_f16x3<<<dim3(16, 64), 256, 0, stream>>>(Qh, Ql, Kh, Kl, Vth, Vtl, Ch, Cl);

  // 4) out-proj + residual(x) -> tmp
  gemm_f16x3<1><<<512, 512, 0, stream>>>(
      Ch, Cl, Woh, Wol, ob, 1024, 1024, tmp, x,
      nullptr, nullptr, nullptr, nullptr, nullptr, nullptr);

  // 5) LN1 + router fused -> h (fp32) + h_bf + assign
  ln_router_kernel<<<8192, 256, 0, stream>>>(tmp, g1, b1n, hbuf, hbf,
                                             rw, rb, assign);

  // 6) bucket tokens per expert (parallel)
  zero_kernel<<<1, 64, 0, stream>>>(counts);
  count_kernel<<<32, 256, 0, stream>>>(assign, counts);
  scatter_kernel<<<32, 256, 0, stream>>>(assign, counts, list);

  // 7) MoE FFN (bf16): he = gelu(h@w1^T+b1) ; tmp = h + (he@w2^T+b2)
  gemm_moe<2><<<4096, 512, 0, stream>>>(
      hbf, w1b, b1e, nullptr, nullptr, he, list, counts);
  gemm_moe<3><<<4096, 512, 0, stream>>>(
      he, w2b, b2e, hbuf, tmp, nullptr, list, counts);

  // 8) LN2 -> d_out
  ln_kernel<<<8192, 256, 0, stream>>>(tmp, g2, b2n, (float*)d_out);
}

// Round 16
// 665.298 us; speedup vs baseline: 1.0121x; 1.0002x over previous
//
#include <hip/hip_runtime.h>
#include <math.h>

// ---------------------------------------------------------------------------
// StandardMoELayer on MI355X.
// Precision: fp16x3 split-MFMA upstream of router; bf16 MFMA post-router.
// R16: gemm_moe -> tri-buffer counted-vmcnt pipeline (R11 protocol, proven
// correct): 48KB LDS, 2-deep prefetch, vmcnt(2)+raw barrier. Gathered A rows
// (token list) now get two compute phases to cover L2-miss latency.
// gemm_f16x3 untouched (R11: depth is a no-op there; tri-buffer would cost
// a resident block).
// ---------------------------------------------------------------------------

typedef __attribute__((ext_vector_type(4))) float f32x4;
typedef __attribute__((ext_vector_type(8))) _Float16 f16x8;
typedef __attribute__((ext_vector_type(4))) _Float16 f16x4;
typedef __attribute__((ext_vector_type(8))) short bf16x8;

#define DEVI static __device__ __forceinline__

DEVI unsigned short f2bf(float f) {
  unsigned int u = __builtin_bit_cast(unsigned int, f);
  return (unsigned short)((u + 0x7fffu + ((u >> 16) & 1u)) >> 16);
}

DEVI f32x4 fzero4() { f32x4 z; z[0]=0.f; z[1]=0.f; z[2]=0.f; z[3]=0.f; return z; }

DEVI void splitf16(float v, _Float16* hi, _Float16* lo) {
  _Float16 h = (_Float16)v;
  *hi = h;
  *lo = (_Float16)(v - (float)h);
}

DEVI void gload16(const void* g, void* l) {
  __builtin_amdgcn_global_load_lds(
      (__attribute__((address_space(1))) void*)(g),
      (__attribute__((address_space(3))) void*)(l), 16, 0, 0);
}

// ---------------------------------------------------------------------------
// fused elementwise prep: x/ipw/ow fp16-split + w1/w2 bf16 cast, one launch
// ---------------------------------------------------------------------------
DEVI void do_split(const float* __restrict__ in, _Float16* __restrict__ oh,
                   _Float16* __restrict__ ol, float scale, int i) {
  float4 v = ((const float4*)in)[i];
  f16x4 hv, lv; _Float16 hh, ll;
  splitf16(v.x * scale, &hh, &ll); hv[0]=hh; lv[0]=ll;
  splitf16(v.y * scale, &hh, &ll); hv[1]=hh; lv[1]=ll;
  splitf16(v.z * scale, &hh, &ll); hv[2]=hh; lv[2]=ll;
  splitf16(v.w * scale, &hh, &ll); hv[3]=hh; lv[3]=ll;
  ((f16x4*)oh)[i] = hv;
  ((f16x4*)ol)[i] = lv;
}

DEVI void do_castbf(const float* __restrict__ in, unsigned short* __restrict__ o,
                    int i) {
  float4 v = ((const float4*)in)[i];
  ushort4 r;
  r.x = f2bf(v.x); r.y = f2bf(v.y); r.z = f2bf(v.z); r.w = f2bf(v.w);
  ((ushort4*)o)[i] = r;
}

__global__ void prep_kernel(const float* __restrict__ x,
                            _Float16* __restrict__ Xh, _Float16* __restrict__ Xl,
                            const float* __restrict__ ipw,
                            _Float16* __restrict__ Wih, _Float16* __restrict__ Wil,
                            const float* __restrict__ ow,
                            _Float16* __restrict__ Woh, _Float16* __restrict__ Wol,
                            const float* __restrict__ w1, unsigned short* __restrict__ w1b,
                            const float* __restrict__ w2, unsigned short* __restrict__ w2b) {
  int b = blockIdx.x, tid = threadIdx.x;
  if (b < 8192)        do_split(x,   Xh,  Xl,  2048.0f, b * 256 + tid);
  else if (b < 11264)  do_split(ipw, Wih, Wil, 1024.0f, (b - 8192) * 256 + tid);
  else if (b < 12288)  do_split(ow,  Woh, Wol, 1024.0f, (b - 11264) * 256 + tid);
  else if (b < 20480)  do_castbf(w1, w1b, (b - 12288) * 256 + tid);
  else                 do_castbf(w2, w2b, (b - 20480) * 256 + tid);
}

// ---------------------------------------------------------------------------
// fp16x3 GEMM: C[M=8192,N] = A[M,K] * W[N,K]^T  (A scaled 2^11, W scaled 2^10)
// 128x128 tile, BK=32, 512 threads = 8 waves (2x4), 64x32 out per wave.
// Double-buffered global_load_lds pipeline (vmcnt(0)+syncthreads, replay-safe)
// XCD-chunked grid. EPI 0: two-pass LDS-restage coalesced Q/K/V^T split-store.
// EPI 1: +bias +res -> fp32 out.
// ---------------------------------------------------------------------------
template<int EPI>
__global__ __launch_bounds__(512) void gemm_f16x3(
    const _Float16* __restrict__ Ah, const _Float16* __restrict__ Al,
    const _Float16* __restrict__ Bh, const _Float16* __restrict__ Bl,
    const float* __restrict__ bias, int N, int K,
    float* __restrict__ out_f, const float* __restrict__ res,
    _Float16* __restrict__ Qh, _Float16* __restrict__ Ql,
    _Float16* __restrict__ Kh, _Float16* __restrict__ Kl,
    _Float16* __restrict__ Vh, _Float16* __restrict__ Vl) {
  __shared__ __align__(16) char smem[65536];  // 2 buf x (4 arrays x 128 x 64 B)
  const int tid = threadIdx.x;
  const int lane = tid & 63, wave = tid >> 6;   // 0..7
  const int wm = wave >> 2, wn = wave & 3;      // 2 x 4 wave grid
  const int qr = lane & 15, lq = lane >> 4;

  // XCD-chunked block remap (nwg % 8 == 0 here)
  const int xcd = blockIdx.x & 7, idx = blockIdx.x >> 3;
  const int colsPerX = (N >> 7) >> 3;
  const int rowb = idx / colsPerX;
  const int colb = xcd * colsPerX + (idx - rowb * colsPerX);
  const int rowBase = rowb * 128, colBase = colb * 128;

  // staging: 1 granule-swizzled 16B chunk per array per thread.
  const char* gsrc[4];
  unsigned ldso[4];
  {
    const int row = tid >> 2;
    const int gs = (tid & 3) ^ ((row >> 1) & 3);
#pragma unroll
    for (int a = 0; a < 4; ++a) {
      const _Float16* basep = (a == 0) ? Ah : (a == 1) ? Al : (a == 2) ? Bh : Bl;
      int R0 = (a < 2) ? rowBase : colBase;
      gsrc[a] = (const char*)(basep + (size_t)(R0 + row) * K) + gs * 16;
      ldso[a] = a * 8192 + wave * 1024;  // wave-uniform
    }
  }

  f32x4 acc[4][2];
#pragma unroll
  for (int m = 0; m < 4; ++m)
#pragma unroll
    for (int n = 0; n < 2; ++n) acc[m][n] = fzero4();

  const int gfr = (qr >> 1) & 3;  // frag granule swizzle term
  const int NT = K >> 5;
  // prologue: stage tile 0 into buf 0
#pragma unroll
  for (int a = 0; a < 4; ++a) gload16(gsrc[a], smem + ldso[a]);
#pragma unroll
  for (int a = 0; a < 4; ++a) gsrc[a] += 64;

  for (int kt = 0; kt < NT; ++kt) {
    asm volatile("s_waitcnt vmcnt(0)" ::: "memory");  // explicit DMA drain
    __syncthreads();  // tile kt resident in buf[kt&1]
    const unsigned cur = (unsigned)(kt & 1) << 15;
    const unsigned nxt = cur ^ 32768u;
    if (kt + 1 < NT) {
#pragma unroll
      for (int a = 0; a < 4; ++a) gload16(gsrc[a], smem + nxt + ldso[a]);
#pragma unroll
      for (int a = 0; a < 4; ++a) gsrc[a] += 64;
    }
    f16x8 ahf[4], alf[4], bhf[2], blf[2];
#pragma unroll
    for (int mt = 0; mt < 4; ++mt) {
      unsigned off = cur + (wm * 64 + mt * 16 + qr) * 64 + ((lq ^ gfr) * 16);
      ahf[mt] = *(const f16x8*)(smem + off);
      alf[mt] = *(const f16x8*)(smem + 8192 + off);
    }
#pragma unroll
    for (int nt = 0; nt < 2; ++nt) {
      unsigned off = cur + (wn * 32 + nt * 16 + qr) * 64 + ((lq ^ gfr) * 16);
      bhf[nt] = *(const f16x8*)(smem + 16384 + off);
      blf[nt] = *(const f16x8*)(smem + 24576 + off);
    }
#pragma unroll
    for (int mt = 0; mt < 4; ++mt)
#pragma unroll
      for (int nt = 0; nt < 2; ++nt) {
        f32x4 c = acc[mt][nt];
        c = __builtin_amdgcn_mfma_f32_16x16x32_f16(ahf[mt], bhf[nt], c, 0, 0, 0);
        c = __builtin_amdgcn_mfma_f32_16x16x32_f16(ahf[mt], blf[nt], c, 0, 0, 0);
        c = __builtin_amdgcn_mfma_f32_16x16x32_f16(alf[mt], bhf[nt], c, 0, 0, 0);
        acc[mt][nt] = c;
      }
  }

  const float inv21 = 1.0f / 2097152.0f;  // 2^-21
  float biasv[2];
#pragma unroll
  for (int nt = 0; nt < 2; ++nt) biasv[nt] = bias[colBase + wn * 32 + nt * 16 + qr];

  if (EPI == 0) {
    __syncthreads();  // staging LDS reusable now
    const int sect = colBase >> 10;                // 0=Q 1=K 2=V (block-uniform)
    const int hhBase = (colBase & 1023) >> 6;
    const int t0 = rowBase >> 3;
    _Float16* L = (_Float16*)smem;                 // 16384 fp16 = 32 KB
    _Float16* dstH = (sect == 0) ? Qh : (sect == 1) ? Kh : Vh;
    _Float16* dstL = (sect == 0) ? Ql : (sect == 1) ? Kl : Vl;
#pragma unroll
    for (int pass = 0; pass < 2; ++pass) {
      if (pass) __syncthreads();
      // scatter acc into LDS in output-linear layout
#pragma unroll
      for (int mt = 0; mt < 4; ++mt)
#pragma unroll
        for (int nt = 0; nt < 2; ++nt)
#pragma unroll
          for (int r = 0; r < 4; ++r) {
            int rl = wm * 64 + mt * 16 + lq * 4 + r;
            int cl = wn * 32 + nt * 16 + qr;
            float v = acc[mt][nt][r] * inv21 + biasv[nt];
            _Float16 h_, l_;
            splitf16(v * 2048.0f, &h_, &l_);
            int off;
            if (sect < 2)
              off = ((rl & 7) * 2 + (cl >> 6)) * 1024 + (rl >> 3) * 64 + (cl & 63);
            else  // granule XOR-swizzle: kills 16-way bank conflict
              off = (cl >> 6) * 8192 + (cl & 63) * 128 +
                    (((rl & 7) ^ (cl & 7)) * 16) + (rl >> 3);
            L[off] = pass ? l_ : h_;
          }
      __syncthreads();
      _Float16* dst = pass ? dstL : dstH;
      if (sect < 2) {
#pragma unroll
        for (int j = 0; j < 4; ++j) {
          int c = j * 512 + tid;                   // 16B chunk id, 0..2047
          int b = c >> 8, hh = (c >> 7) & 1;
          int tl = (c >> 3) & 15, dd = (c & 7) * 8;
          size_t gd = ((size_t)(b * 16 + hhBase + hh) << 16) +
                      (size_t)(t0 + tl) * 64 + dd;
          *(uint4*)(dst + gd) = *(const uint4*)(L + (size_t)c * 8);
        }
      } else {
#pragma unroll
        for (int j = 0; j < 2; ++j) {
          int c = j * 512 + tid;                   // 32B chunk id, 0..1023
          int hh = c >> 9, dd = (c >> 3) & 63, b = c & 7;
          size_t gd = ((size_t)(b * 16 + hhBase + hh) << 16) +
                      (size_t)dd * 1024 + t0;
          int gb = hh * 8192 + dd * 128 + ((b ^ (dd & 7)) * 16);
          *(uint4*)(dst + gd)     = *(const uint4*)(L + gb);
          *(uint4*)(dst + gd + 8) = *(const uint4*)(L + gb + 8);
        }
      }
    }
  } else {
#pragma unroll
    for (int mt = 0; mt < 4; ++mt)
#pragma unroll
      for (int nt = 0; nt < 2; ++nt)
#pragma unroll
        for (int r = 0; r < 4; ++r) {
          int grow = rowBase + wm * 64 + mt * 16 + lq * 4 + r;
          int col = colBase + wn * 32 + nt * 16 + qr;
          size_t o = (size_t)grow * N + col;
          out_f[o] = acc[mt][nt][r] * inv21 + biasv[nt] + res[o];
        }
  }
}

// ---------------------------------------------------------------------------
// flash attention, fp16x3, fixed-m softmax (P = exp(s-8), scores << 8).
// QT=2: two 64-row Q-tiles per block share one K/V staging stream.
// KVBLK=32, double-buffered K/V via global_load_lds; vmcnt(0)+barrier.
// LDS 50176 B -> 3 blocks/CU. grid 1024 XCD-remapped.
// ---------------------------------------------------------------------------
__global__ __launch_bounds__(256) void attn_f16x3(
    const _Float16* __restrict__ Qh, const _Float16* __restrict__ Ql,
    const _Float16* __restrict__ Kh, const _Float16* __restrict__ Kl,
    const _Float16* __restrict__ Vth, const _Float16* __restrict__ Vtl,
    _Float16* __restrict__ Ch, _Float16* __restrict__ Cl) {
  __shared__ __align__(16) char smem[50176];
  const int tid = threadIdx.x;
  const int lane = tid & 63, wave = tid >> 6;
  const int qr = lane & 15, lq = lane >> 4;
  // XCD remap: lin%8 = XCD -> contiguous bh range per XCD (K/V L2-resident)
  const int lin = blockIdx.y * 16 + blockIdx.x;
  const int xcd = lin & 7, k6 = lin >> 3;        // k6: 0..127
  const int bh = xcd * 16 + (k6 >> 3);
  const int qp = k6 & 7;                         // q-pair tile, 128 rows
  const size_t bo = (size_t)bh * 65536;
  const _Float16* Qhp = Qh + bo; const _Float16* Qlp = Ql + bo;
  const _Float16* Khp = Kh + bo; const _Float16* Klp = Kl + bo;
  const _Float16* Vhp = Vth + bo; const _Float16* Vlp = Vtl + bo;
  const int q0 = qp * 128 + wave * 16;           // tile t adds t*64

  f16x8 qhf[2][2], qlf[2][2];                    // [tile][kc]
#pragma unroll
  for (int t = 0; t < 2; ++t)
#pragma unroll
    for (int kc = 0; kc < 2; ++kc) {
      size_t qo = (size_t)(q0 + t*64 + qr) * 64 + kc*32 + lq*8;
      qhf[t][kc] = *(const f16x8*)(Qhp + qo);
      qlf[t][kc] = *(const f16x8*)(Qlp + qo);
    }
  f16x8 ones;
#pragma unroll
  for (int j = 0; j < 8; ++j) ones[j] = (_Float16)1.0f;

  f32x4 o0[4], o1[4], osum0, osum1;
#pragma unroll
  for (int i = 0; i < 4; ++i) { o0[i] = fzero4(); o1[i] = fzero4(); }
  osum0 = fzero4(); osum1 = fzero4();

  // staging source (pre-swizzled global addresses; LDS dest linear).
  const int krow = lane >> 3;                      // 0..7 within wave slice
  const int kswz = (lane & 7) ^ krow;
  const _Float16* gKH = Khp + (size_t)(wave*8 + krow) * 64 + kswz * 8;
  const _Float16* gKL = Klp + (size_t)(wave*8 + krow) * 64 + kswz * 8;
  const int vrow = lane >> 2;                      // 0..15 within wave slice
  const int vswz = (lane & 3) ^ (((lane >> 2) & 3) ^ ((lane >> 4) & 3));
  const _Float16* gVH = Vhp + (size_t)(wave*16 + vrow) * 1024 + vswz * 8;
  const _Float16* gVL = Vlp + (size_t)(wave*16 + vrow) * 1024 + vswz * 8;
  const unsigned ldsw = wave * 1024;               // wave-uniform slice base

#define STAGE(kb_, bufo_)                                                     \
  {                                                                           \
    gload16(gKH + (size_t)(kb_) * 2048, smem + (bufo_) + ldsw);               \
    gload16(gKL + (size_t)(kb_) * 2048, smem + 8192 + (bufo_) + ldsw);        \
    gload16(gVH + (size_t)(kb_) * 32, smem + 16384 + (bufo_) + ldsw);         \
    gload16(gVL + (size_t)(kb_) * 32, smem + 24576 + (bufo_) + ldsw);         \
  }

// pack P for one tile into PP, fence, then PV into (o_, osum_)
#define SM_PV(sarr, o_, osum_)                                                \
  {                                                                           \
    _Pragma("unroll")                                                         \
    for (int nt = 0; nt < 2; ++nt)                                            \
      _Pragma("unroll")                                                       \
      for (int r = 0; r < 4; ++r) {                                           \
        float pv = __expf(__builtin_fmaf(sarr[nt][r], sscale, -8.0f)) * 2048.0f; \
        _Float16 ph = (_Float16)pv;                                           \
        _Float16 pl = (_Float16)(pv - (float)ph);                             \
        unsigned pk = (unsigned)__builtin_bit_cast(unsigned short, ph) |      \
                      ((unsigned)__builtin_bit_cast(unsigned short, pl) << 16); \
        *(unsigned*)(ppw + ((lq*4 + r)*68 + nt*16 + qr) * 4) = pk;            \
      }                                                                       \
    asm volatile("s_waitcnt lgkmcnt(0)" ::: "memory");                        \
    __builtin_amdgcn_sched_barrier(0);                                        \
    {                                                                         \
      const uint4* pp = (const uint4*)(ppw + (qr*68 + lq*8) * 4);             \
      uint4 pa = pp[0], pb = pp[1];                                           \
      uint4 hw, lw;                                                           \
      hw.x = __builtin_amdgcn_perm(pa.y, pa.x, 0x05040100u);                  \
      hw.y = __builtin_amdgcn_perm(pa.w, pa.z, 0x05040100u);                  \
      hw.z = __builtin_amdgcn_perm(pb.y, pb.x, 0x05040100u);                  \
      hw.w = __builtin_amdgcn_perm(pb.w, pb.z, 0x05040100u);                  \
      lw.x = __builtin_amdgcn_perm(pa.y, pa.x, 0x07060302u);                  \
      lw.y = __builtin_amdgcn_perm(pa.w, pa.z, 0x07060302u);                  \
      lw.z = __builtin_amdgcn_perm(pb.y, pb.x, 0x07060302u);                  \
      lw.w = __builtin_amdgcn_perm(pb.w, pb.z, 0x07060302u);                  \
      f16x8 pah = __builtin_bit_cast(f16x8, hw);                              \
      f16x8 pal = __builtin_bit_cast(f16x8, lw);                              \
      __builtin_amdgcn_s_setprio(1);                                          \
      _Pragma("unroll")                                                       \
      for (int dt = 0; dt < 4; ++dt) {                                        \
        int voff = cur + (dt*16 + qr)*64 + ((lq ^ vfr) * 16);                 \
        f16x8 vh_ = *(const f16x8*)(smem + 16384 + voff);                     \
        f16x8 vl_ = *(const f16x8*)(smem + 24576 + voff);                     \
        o_[dt] = __builtin_amdgcn_mfma_f32_16x16x32_f16(pah, vh_, o_[dt], 0, 0, 0); \
        o_[dt] = __builtin_amdgcn_mfma_f32_16x16x32_f16(pah, vl_, o_[dt], 0, 0, 0); \
        o_[dt] = __builtin_amdgcn_mfma_f32_16x16x32_f16(pal, vh_, o_[dt], 0, 0, 0); \
      }                                                                       \
      osum_ = __builtin_amdgcn_mfma_f32_16x16x32_f16(pah, ones, osum_, 0, 0, 0); \
      osum_ = __builtin_amdgcn_mfma_f32_16x16x32_f16(pal, ones, osum_, 0, 0, 0); \
      __builtin_amdgcn_s_setprio(0);                                          \
    }                                                                         \
  }

  STAGE(0, 0)
  const float sscale = 2.9802322387695312e-08f;  // 2^-22 * 0.125
  const int vfr = (qr & 3) ^ ((qr >> 2) & 3);    // V frag read swizzle
  char* ppw = smem + 32768 + wave * 4352;        // wave's PP slice

  for (int kb = 0; kb < 32; ++kb) {
    asm volatile("s_waitcnt vmcnt(0)" ::: "memory");  // drain DMA for tile kb
    __syncthreads();               // publish: tile kb resident in buf
    const int cur = (kb & 1) * 4096;
    if (kb + 1 < 32) STAGE(kb + 1, cur ^ 4096)   // flies during compute below

    // QK^T both tiles, sharing K fragment loads
    f32x4 s0[2], s1[2];
    __builtin_amdgcn_s_setprio(1);
#pragma unroll
    for (int nt = 0; nt < 2; ++nt) {
      f32x4 z0 = fzero4(), z1 = fzero4();
      const int r_ = nt*16 + qr;
#pragma unroll
      for (int kc = 0; kc < 2; ++kc) {
        int koff = cur + r_*128 + (((kc*4 + lq) ^ (r_ & 7)) * 16);
        f16x8 kh_ = *(const f16x8*)(smem + koff);
        f16x8 kl_ = *(const f16x8*)(smem + 8192 + koff);
        z0 = __builtin_amdgcn_mfma_f32_16x16x32_f16(qhf[0][kc], kh_, z0, 0, 0, 0);
        z0 = __builtin_amdgcn_mfma_f32_16x16x32_f16(qhf[0][kc], kl_, z0, 0, 0, 0);
        z0 = __builtin_amdgcn_mfma_f32_16x16x32_f16(qlf[0][kc], kh_, z0, 0, 0, 0);
        z1 = __builtin_amdgcn_mfma_f32_16x16x32_f16(qhf[1][kc], kh_, z1, 0, 0, 0);
        z1 = __builtin_amdgcn_mfma_f32_16x16x32_f16(qhf[1][kc], kl_, z1, 0, 0, 0);
        z1 = __builtin_amdgcn_mfma_f32_16x16x32_f16(qlf[1][kc], kh_, z1, 0, 0, 0);
      }
      s0[nt] = z0; s1[nt] = z1;
    }
    __builtin_amdgcn_s_setprio(0);
    SM_PV(s0, o0, osum0)
    SM_PV(s1, o1, osum1)
  }
#undef STAGE
#undef SM_PV
  const int b = bh >> 4, hh = bh & 15;
  // o = 2^22 * P.V ; osum = 2^11 * sum(P)  =>  o/osum = v_true * 2^11 (C scale)
#pragma unroll
  for (int t = 0; t < 2; ++t) {
    f32x4* op = t ? o1 : o0;
    f32x4 osum = t ? osum1 : osum0;
#pragma unroll
    for (int dt = 0; dt < 4; ++dt)
#pragma unroll
      for (int r = 0; r < 4; ++r) {
        int tq = q0 + t*64 + lq*4 + r;
        float v = op[dt][r] / osum[r];
        size_t idx = ((size_t)tq * 8 + b) * 1024 + hh*64 + dt*16 + qr;
        _Float16 h_, l_;
        splitf16(v, &h_, &l_);
        Ch[idx] = h_; Cl[idx] = l_;
      }
  }
}

// ---------------------------------------------------------------------------
// LayerNorm over C=1024. one block per row. (LN2 path)
// ---------------------------------------------------------------------------
__global__ __launch_bounds__(256) void ln_kernel(
    const float* __restrict__ in, const float* __restrict__ g,
    const float* __restrict__ b, float* __restrict__ outf) {
  int row = blockIdx.x, tid = threadIdx.x;
  const float* xr = in + (size_t)row * 1024;
  float4 v = *(const float4*)(xr + tid*4);
  float s  = v.x + v.y + v.z + v.w;
  float sq = v.x*v.x + v.y*v.y + v.z*v.z + v.w*v.w;
#pragma unroll
  for (int off = 1; off < 64; off <<= 1) {
    s  += __shfl_xor(s, off, 64);
    sq += __shfl_xor(sq, off, 64);
  }
  __shared__ float red[8];
  int wv = tid >> 6, ln = tid & 63;
  if (ln == 0) { red[wv] = s; red[4 + wv] = sq; }
  __syncthreads();
  s  = red[0] + red[1] + red[2] + red[3];
  sq = red[4] + red[5] + red[6] + red[7];
  float mu   = s * 0.0009765625f;
  float var  = sq * 0.0009765625f - mu * mu;
  float rstd = 1.0f / sqrtf(var + 1e-5f);
  float4 gv = *(const float4*)(g + tid*4);
  float4 bv = *(const float4*)(b + tid*4);
  float4 o;
  o.x = (v.x - mu) * rstd * gv.x + bv.x;
  o.y = (v.y - mu) * rstd * gv.y + bv.y;
  o.z = (v.z - mu) * rstd * gv.z + bv.z;
  o.w = (v.w - mu) * rstd * gv.w + bv.w;
  *(float4*)(outf + (size_t)row * 1024 + tid*4) = o;
}

// ---------------------------------------------------------------------------
// LN1 + router fused (bit-exact router summation, see R14 notes).
// ---------------------------------------------------------------------------
__global__ __launch_bounds__(256) void ln_router_kernel(
    const float* __restrict__ in, const float* __restrict__ g,
    const float* __restrict__ b, float* __restrict__ outf,
    unsigned short* __restrict__ outbf,
    const float* __restrict__ rw, const float* __restrict__ rb,
    int* __restrict__ assign) {
  int row = blockIdx.x, tid = threadIdx.x;
  const float* xr = in + (size_t)row * 1024;
  float4 v = *(const float4*)(xr + tid*4);
  float s  = v.x + v.y + v.z + v.w;
  float sq = v.x*v.x + v.y*v.y + v.z*v.z + v.w*v.w;
#pragma unroll
  for (int off = 1; off < 64; off <<= 1) {
    s  += __shfl_xor(s, off, 64);
    sq += __shfl_xor(sq, off, 64);
  }
  __shared__ float red[8];
  __shared__ float D[4][8][64];
  int wv = tid >> 6, ln = tid & 63;
  if (ln == 0) { red[wv] = s; red[4 + wv] = sq; }
  __syncthreads();
  s  = red[0] + red[1] + red[2] + red[3];
  sq = red[4] + red[5] + red[6] + red[7];
  float mu   = s * 0.0009765625f;
  float var  = sq * 0.0009765625f - mu * mu;
  float rstd = 1.0f / sqrtf(var + 1e-5f);
  float4 gv = *(const float4*)(g + tid*4);
  float4 bv = *(const float4*)(b + tid*4);
  float4 o;
  o.x = (v.x - mu) * rstd * gv.x + bv.x;
  o.y = (v.y - mu) * rstd * gv.y + bv.y;
  o.z = (v.z - mu) * rstd * gv.z + bv.z;
  o.w = (v.w - mu) * rstd * gv.w + bv.w;
  *(float4*)(outf + (size_t)row * 1024 + tid*4) = o;
  ushort4 ob;
  ob.x = f2bf(o.x); ob.y = f2bf(o.y); ob.z = f2bf(o.z); ob.w = f2bf(o.w);
  *(ushort4*)(outbf + (size_t)row * 1024 + tid*4) = ob;
  // router partials: same dot expression as old router_kernel
#pragma unroll
  for (int e = 0; e < 8; ++e) {
    float4 wvv = *(const float4*)(rw + e*1024 + tid*4);
    D[wv][e][ln] = o.x*wvv.x + o.y*wvv.y + o.z*wvv.z + o.w*wvv.w;
  }
  __syncthreads();
  if (wv == 0) {
    float acc[8];
#pragma unroll
    for (int e = 0; e < 8; ++e) {
      float a0 = D[0][e][ln];        // j=0..3 ascending, left-assoc (router order)
      a0 += D[1][e][ln];
      a0 += D[2][e][ln];
      a0 += D[3][e][ln];
      acc[e] = a0;
    }
#pragma unroll
    for (int e = 0; e < 8; ++e) {
#pragma unroll
      for (int off = 1; off < 64; off <<= 1) acc[e] += __shfl_xor(acc[e], off, 64);
      acc[e] += rb[e];
    }
    if (ln == 0) {
      int i1 = 0; float v1 = acc[0];
#pragma unroll
      for (int e = 1; e < 8; ++e) if (acc[e] > v1) { v1 = acc[e]; i1 = e; }
      int i2 = -1; float v2 = -3.0e38f;
#pragma unroll
      for (int e = 0; e < 8; ++e) if (e != i1 && acc[e] > v2) { v2 = acc[e]; i2 = e; }
      assign[row] = (i1 > i2) ? i1 : i2;
    }
  }
}

// ---------------------------------------------------------------------------
// expert bucketing: parallel zero/count/scatter.
// ---------------------------------------------------------------------------
__global__ void zero_kernel(int* __restrict__ counts) {
  if (threadIdx.x < 16) counts[threadIdx.x] = 0;
}
__global__ void count_kernel(const int* __restrict__ assign, int* __restrict__ counts) {
  int i = blockIdx.x * 256 + threadIdx.x;
  if (i < 8192) atomicAdd(&counts[assign[i]], 1);
}
__global__ void scatter_kernel(const int* __restrict__ assign, int* __restrict__ counts,
                               int* __restrict__ list) {
  int i = blockIdx.x * 256 + threadIdx.x;
  if (i >= 8192) return;
  int a = assign[i];
  int base = 0;
  for (int e = 0; e < a; ++e) base += counts[e];
  int pos = atomicAdd(&counts[8 + a], 1);
  list[base + pos] = i;
}

// ---------------------------------------------------------------------------
// grouped MoE GEMM, bf16. 1-D grid 4096: expert = blk&7 (XCD-pinned),
// colb = (blk>>3)&7, rowb = blk>>6. 128x128 tile, BK=32, 512 threads/8 waves,
// 64x32 out per wave. R16: TRI-buffered global_load_lds, 2-deep prefetch,
// counted vmcnt(2) + raw s_barrier (R11 protocol) — gathered A rows get two
// compute phases of latency cover. LDS 48KB.
// ---------------------------------------------------------------------------
template<int EPI>
__global__ __launch_bounds__(512) void gemm_moe(
    const unsigned short* __restrict__ A, const unsigned short* __restrict__ Bw,
    const float* __restrict__ bias, const float* __restrict__ res,
    float* __restrict__ out_f, unsigned short* __restrict__ out_bf,
    const int* __restrict__ list, const int* __restrict__ counts) {
  const int lin = blockIdx.x;
  const int e = lin & 7;                 // expert -> XCD pinned
  const int colb = (lin >> 3) & 7;
  const int rowb = lin >> 6;             // 0..63
  const int cnt = counts[e];
  if (rowb * 128 >= cnt) return;
  int base = 0;
  for (int i = 0; i < 8; ++i) if (i < e) base += counts[i];
  const unsigned short* Bp = Bw + (size_t)e * 1048576;
  const float* biasp = bias + e * 1024;

  __shared__ __align__(16) char smem[49152];  // 3 buf x (A 8KB + B 8KB)
  const int tid = threadIdx.x;
  const int lane = tid & 63, wave = tid >> 6;
  const int wm = wave >> 2, wn = wave & 3;     // 2 x 4 wave grid
  const int qr = lane & 15, lq = lane >> 4;
  const int rowBase = rowb * 128, colBase = colb * 128;

  const char *gA, *gB;
  {
    const int row = tid >> 2;
    const int gs = (tid & 3) ^ ((row >> 1) & 3);
    int grow = rowBase + row;
    int gi = (grow < cnt) ? grow : (cnt - 1);
    int arow = (EPI == 2) ? list[base + gi] : (base + gi);
    gA = (const char*)(A + (size_t)arow * 1024) + gs * 16;
    gB = (const char*)(Bp + (size_t)(colBase + row) * 1024) + gs * 16;
  }
  const unsigned ldsoA = wave * 1024;          // wave-uniform (lane*16 by HW)
  const unsigned ldsoB = 8192 + wave * 1024;

  f32x4 acc[4][2];
#pragma unroll
  for (int m = 0; m < 4; ++m)
#pragma unroll
    for (int n = 0; n < 2; ++n) acc[m][n] = fzero4();

  const int gfr = (qr >> 1) & 3;
  // prologue: stage tiles 0,1 into buf 0,1 (4 loads in flight / thread)
  gload16(gA, smem + ldsoA);
  gload16(gB, smem + ldsoB);
  gA += 64; gB += 64;
  gload16(gA, smem + 16384 + ldsoA);
  gload16(gB, smem + 16384 + ldsoB);
  gA += 64; gB += 64;

  int bcur = 0;
  for (int kt = 0; kt < 32; ++kt) {
    // wait ONLY tile kt's 2 loads (oldest); tile kt+1's 2 stay in flight
    if (kt + 1 < 32) asm volatile("s_waitcnt vmcnt(2)" ::: "memory");
    else             asm volatile("s_waitcnt vmcnt(0)" ::: "memory");
    __builtin_amdgcn_s_barrier();     // publish tile kt (raw: no vmcnt drain)
    __builtin_amdgcn_sched_barrier(0);
    if (kt + 2 < 32) {
      int bnx = bcur + 2; if (bnx >= 3) bnx -= 3;
      const unsigned bo = (unsigned)bnx * 16384u;
      gload16(gA, smem + bo + ldsoA);
      gload16(gB, smem + bo + ldsoB);
      gA += 64; gB += 64;
    }
    const unsigned cur = (unsigned)bcur * 16384u;
    bf16x8 af[4], bf[2];
#pragma unroll
    for (int mt = 0; mt < 4; ++mt) {
      unsigned off = cur + (wm * 64 + mt * 16 + qr) * 64 + ((lq ^ gfr) * 16);
      af[mt] = *(const bf16x8*)(smem + off);
    }
#pragma unroll
    for (int nt = 0; nt < 2; ++nt) {
      unsigned off = cur + 8192 + (wn * 32 + nt * 16 + qr) * 64 + ((lq ^ gfr) * 16);
      bf[nt] = *(const bf16x8*)(smem + off);
    }
#pragma unroll
    for (int mt = 0; mt < 4; ++mt)
#pragma unroll
      for (int nt = 0; nt < 2; ++nt)
        acc[mt][nt] = __builtin_amdgcn_mfma_f32_16x16x32_bf16(
            af[mt], bf[nt], acc[mt][nt], 0, 0, 0);
    bcur = (bcur + 1 == 3) ? 0 : bcur + 1;
  }

#pragma unroll
  for (int mt = 0; mt < 4; ++mt)
#pragma unroll
    for (int nt = 0; nt < 2; ++nt)
#pragma unroll
      for (int r = 0; r < 4; ++r) {
        int grow = rowBase + wm * 64 + mt * 16 + lq * 4 + r;
        int col  = colBase + wn * 32 + nt * 16 + qr;
        if (grow < cnt) {
          float v = acc[mt][nt][r] + biasp[col];
          if (EPI == 2) {
            float ge = 0.5f * v * (1.0f + erff(v * 0.70710678118654752f));
            out_bf[(size_t)(base + grow) * 1024 + col] = f2bf(ge);
          } else {
            int n = list[base + grow];
            size_t o2 = (size_t)n * 1024 + col;
            out_f[o2] = v + res[o2];
          }
        }
      }
}

// ---------------------------------------------------------------------------
extern "C" void kernel_launch(void* const* d_in, const int* in_sizes, int n_in,
                              void* d_out, int out_size, void* d_ws, size_t ws_size,
                              hipStream_t stream) {
  const float* x   = (const float*)d_in[0];
  const float* ipw = (const float*)d_in[1];
  const float* ipb = (const float*)d_in[2];
  const float* ow  = (const float*)d_in[3];
  const float* ob  = (const float*)d_in[4];
  const float* g1  = (const float*)d_in[5];
  const float* b1n = (const float*)d_in[6];
  const float* rw  = (const float*)d_in[7];
  const float* rb  = (const float*)d_in[8];
  const float* w1  = (const float*)d_in[9];
  const float* b1e = (const float*)d_in[10];
  const float* w2  = (const float*)d_in[11];
  const float* b2e = (const float*)d_in[12];
  const float* g2  = (const float*)d_in[13];
  const float* b2n = (const float*)d_in[14];

  char* ws = (char*)d_ws;
  const size_t MB = 1048576;
  _Float16* Xh  = (_Float16*)(ws + 0*MB);
  _Float16* Xl  = (_Float16*)(ws + 16*MB);
  _Float16* Wih = (_Float16*)(ws + 32*MB);
  _Float16* Wil = (_Float16*)(ws + 38*MB);
  _Float16* Woh = (_Float16*)(ws + 44*MB);
  _Float16* Wol = (_Float16*)(ws + 46*MB);
  unsigned short* w1b = (unsigned short*)(ws + 48*MB);
  unsigned short* w2b = (unsigned short*)(ws + 64*MB);
  _Float16* Qh  = (_Float16*)(ws + 80*MB);
  _Float16* Ql  = (_Float16*)(ws + 96*MB);
  _Float16* Kh  = (_Float16*)(ws + 112*MB);
  _Float16* Kl  = (_Float16*)(ws + 128*MB);
  _Float16* Vth = (_Float16*)(ws + 144*MB);
  _Float16* Vtl = (_Float16*)(ws + 160*MB);
  // overlays of dead regions:
  _Float16* Ch  = Xh;                                     // ctx hi (X dead)
  _Float16* Cl  = Xl;                                     // ctx lo
  float* tmp    = (float*)(ws + 80*MB);                   // over Q (dead post-attn)
  float* hbuf   = (float*)(ws + 112*MB);                  // over K
  unsigned short* hbf = (unsigned short*)(ws + 144*MB);   // over Vth
  unsigned short* he  = (unsigned short*)(ws + 160*MB);   // over Vtl
  int* assign = (int*)(ws + 176*MB);
  int* list   = (int*)(ws + 176*MB + 32768);
  int* counts = (int*)(ws + 176*MB + 65536);

  // 1) fused precision-split / cast
  prep_kernel<<<28672, 256, 0, stream>>>(x, Xh, Xl, ipw, Wih, Wil,
                                         ow, Woh, Wol, w1, w1b, w2, w2b);

  // 2) QKV projection (fp16x3), coalesced scatter epilogue
  gemm_f16x3<0><<<1536, 512, 0, stream>>>(
      Xh, Xl, Wih, Wil, ipb, 3072, 1024, nullptr, nullptr,
      Qh, Ql, Kh, Kl, Vth, Vtl);

  // 3) flash attention (QT=2: 1024 blocks)
  attn_f16x3<<<dim3(16, 64), 256, 0, stream>>>(Qh, Ql, Kh, Kl, Vth, Vtl, Ch, Cl);

  // 4) out-proj + residual(x) -> tmp
  gemm_f16x3<1><<<512, 512, 0, stream>>>(
      Ch, Cl, Woh, Wol, ob, 1024, 1024, tmp, x,
      nullptr, nullptr, nullptr, nullptr, nullptr, nullptr);

  // 5) LN1 + router fused -> h (fp32) + h_bf + assign
  ln_router_kernel<<<8192, 256, 0, stream>>>(tmp, g1, b1n, hbuf, hbf,
                                             rw, rb, assign);

  // 6) bucket tokens per expert (parallel)
  zero_kernel<<<1, 64, 0, stream>>>(counts);
  count_kernel<<<32, 256, 0, stream>>>(assign, counts);
  scatter_kernel<<<32, 256, 0, stream>>>(assign, counts, list);

  // 7) MoE FFN (bf16): he = gelu(h@w1^T+b1) ; tmp = h + (he@w2^T+b2)
  gemm_moe<2><<<4096, 512, 0, stream>>>(
      hbf, w1b, b1e, nullptr, nullptr, he, list, counts);
  gemm_moe<3><<<4096, 512, 0, stream>>>(
      he, w2b, b2e, hbuf, tmp, nullptr, list, counts);

  // 8) LN2 -> d_out
  ln_kernel<<<8192, 256, 0, stream>>>(tmp, g2, b2n, (float*)d_out);
}